// Round 7
// baseline (752.928 us; speedup 1.0000x reference)
//
#include <hip/hip_runtime.h>
#include <math.h>

#define DM 1024
#define DF 4096
#define NE 24
#define T_TOK 4096
#define T2 (T_TOK*2)

#define BM 128
#define BN 128
#define BK 64
#define MTILES 8
#define NK1 (DM / BK)   // 16
#define NK2 (DF / BK)   // 64

typedef __attribute__((ext_vector_type(4))) float f32x4;
typedef __attribute__((ext_vector_type(8))) short s16x8;

// exact RNE fp32 -> bf16 (finite inputs)
static __device__ __forceinline__ unsigned short f2bf(float f) {
    unsigned int u = __float_as_uint(f);
    unsigned int r = u + 0x7fffu + ((u >> 16) & 1u);
    return (unsigned short)(r >> 16);
}

// async global->LDS, 16B per lane; lds dest is wave-uniform base + lane*16
#define GLL(gsrc, ldst)                                                          \
    __builtin_amdgcn_global_load_lds(                                            \
        (const __attribute__((address_space(1))) void*)(gsrc),                   \
        (__attribute__((address_space(3))) void*)(ldst), 16, 0, 0)

// ---------------- gating ----------------

__global__ void k_transpose_gw(const float* __restrict__ gw, float* __restrict__ gwT) {
    int e = blockIdx.x;
    for (int d = threadIdx.x; d < DM; d += blockDim.x)
        gwT[e * DM + d] = gw[d * NE + e];
}

__global__ void k_gate(const float* __restrict__ x, const float* __restrict__ gwT,
                       const float* __restrict__ gb,
                       int* __restrict__ idx, float* __restrict__ prob) {
    int wave = threadIdx.x >> 6;
    int lane = threadIdx.x & 63;
    int t = blockIdx.x * 4 + wave;
    if (t >= T_TOK) return;
    const float* xr = x + (size_t)t * DM;
    float acc[NE];
#pragma unroll
    for (int e = 0; e < NE; e++) acc[e] = 0.f;
    for (int i = 0; i < DM / 64; i++) {
        int d = lane + i * 64;
        float xv = xr[d];
#pragma unroll
        for (int e = 0; e < NE; e++) acc[e] = fmaf(xv, gwT[e * DM + d], acc[e]);
    }
#pragma unroll
    for (int e = 0; e < NE; e++) {
        float v = acc[e];
        for (int off = 32; off >= 1; off >>= 1) v += __shfl_xor(v, off);
        acc[e] = v;
    }
    if (lane == 0) {
        float v1 = -1e30f, v2 = -1e30f;
        int i1 = -1, i2 = -1;
        for (int e = 0; e < NE; e++) {
            float s = acc[e] + gb[e];
            if (s > v1) { v2 = v1; i2 = i1; v1 = s; i1 = e; }
            else if (s > v2) { v2 = s; i2 = e; }
        }
        float e2 = expf(v2 - v1);
        float inv = 1.f / (1.f + e2);
        idx[t * 2] = i1; idx[t * 2 + 1] = i2;
        prob[t * 2] = inv; prob[t * 2 + 1] = e2 * inv;
    }
}

// ---------------- routing: count + scan + scatter in one block ----------------

__global__ __launch_bounds__(1024)
void k_route(const int* __restrict__ idx, int* __restrict__ counts,
             int* __restrict__ offsets, int* __restrict__ slot_tok,
             int* __restrict__ pair_slot) {
    __shared__ int cnt[NE], offs[NE], cur[NE];
    const int tid = threadIdx.x;
    if (tid < NE) cnt[tid] = 0;
    __syncthreads();
    for (int i = tid; i < T2; i += 1024) atomicAdd(&cnt[idx[i]], 1);
    __syncthreads();
    if (tid == 0) {
        int s = 0;
        for (int e = 0; e < NE; e++) {
            offs[e] = s; offsets[e] = s; counts[e] = cnt[e]; s += cnt[e];
        }
    }
    if (tid < NE) cur[tid] = 0;
    __syncthreads();
    for (int i = tid; i < T2; i += 1024) {
        int e = idx[i];
        int pos = offs[e] + atomicAdd(&cur[e], 1);
        slot_tok[pos] = i >> 1;
        pair_slot[i] = pos;
    }
}

// gather routed token rows into dense bf16 slot-major matrix Xg[slot][DM]
__global__ void k_gather(const float* __restrict__ x, const int* __restrict__ slot_tok,
                         unsigned short* __restrict__ Xg) {
    int s = blockIdx.x;
    int tok = slot_tok[s];
    const float4* src = (const float4*)(x + (size_t)tok * DM);
    ushort4* dst = (ushort4*)(Xg + (size_t)s * DM);
    for (int i = threadIdx.x; i < DM / 4; i += blockDim.x) {
        float4 v = src[i];
        ushort4 o;
        o.x = f2bf(v.x); o.y = f2bf(v.y); o.z = f2bf(v.z); o.w = f2bf(v.w);
        dst[i] = o;
    }
}

// out[t] = p1*(Y[s1]+b2[e1]) + p2*(Y[s2]+b2[e2])
__global__ void k_combine(const float* __restrict__ Y, const int* __restrict__ pair_slot,
                          const float* __restrict__ prob, const int* __restrict__ idx,
                          const float* __restrict__ b2, float* __restrict__ out) {
    int t = blockIdx.x;
    int s1 = pair_slot[t * 2], s2 = pair_slot[t * 2 + 1];
    int e1 = idx[t * 2], e2 = idx[t * 2 + 1];
    float p1 = prob[t * 2], p2 = prob[t * 2 + 1];
    const float4* y1 = (const float4*)(Y + (size_t)s1 * DM);
    const float4* y2 = (const float4*)(Y + (size_t)s2 * DM);
    const float4* ba = (const float4*)(b2 + (size_t)e1 * DM);
    const float4* bb = (const float4*)(b2 + (size_t)e2 * DM);
    float4* o = (float4*)(out + (size_t)t * DM);
    int i = threadIdx.x;
    float4 a = y1[i], b = y2[i], c = ba[i], d = bb[i];
    float4 r;
    r.x = p1 * (a.x + c.x) + p2 * (b.x + d.x);
    r.y = p1 * (a.y + c.y) + p2 * (b.y + d.y);
    r.z = p1 * (a.z + c.z) + p2 * (b.z + d.z);
    r.w = p1 * (a.w + c.w) + p2 * (b.w + d.w);
    o[i] = r;
}

// ---------------- fused transpose+convert: W[K][N] fp32 -> WT[N][K] bf16 --------
// one dispatch for W1 (z<NE) and W2 (z>=NE); 64x64 tiles.
// out mapping: 4 lanes cover one 128B output row chunk (16B/lane stores).

__global__ __launch_bounds__(256)
void k_conv(const float* __restrict__ w1, const float* __restrict__ w2,
            unsigned short* __restrict__ W1T, unsigned short* __restrict__ W2T) {
    const int z = blockIdx.y;
    const float* W;
    unsigned short* WT;
    int K, N, n0, k0;
    if (z < NE) {
        W = w1 + (size_t)z * DM * DF;  WT = W1T + (size_t)z * DM * DF;
        K = DM; N = DF;
        n0 = (blockIdx.x & 63) * 64;  k0 = (blockIdx.x >> 6) * 64;
    } else {
        W = w2 + (size_t)(z - NE) * DF * DM;  WT = W2T + (size_t)(z - NE) * DF * DM;
        K = DF; N = DM;
        n0 = (blockIdx.x & 15) * 64;  k0 = (blockIdx.x >> 4) * 64;
    }
    __shared__ float T[64][65];
    const int t = threadIdx.x;
    const int rr = t >> 4, cc = (t & 15) * 4;
#pragma unroll
    for (int p = 0; p < 4; p++) {
        float4 v = *(const float4*)(W + (size_t)(k0 + rr + p * 16) * N + n0 + cc);
        T[rr + p * 16][cc + 0] = v.x;
        T[rr + p * 16][cc + 1] = v.y;
        T[rr + p * 16][cc + 2] = v.z;
        T[rr + p * 16][cc + 3] = v.w;
    }
    __syncthreads();
    const int n = t >> 2, kb = (t & 3) * 16;
#pragma unroll
    for (int p = 0; p < 2; p++) {
        s16x8 o;
#pragma unroll
        for (int j = 0; j < 8; j++)
            o[j] = (short)f2bf(T[kb + p * 8 + j][n]);
        *(s16x8*)(WT + (size_t)(n0 + n) * K + k0 + kb + p * 8) = o;
    }
}

// ---------------- MM1: H = gelu(Xg @ W1T^T + b1)  [global_load_lds, dbuf] --------
// 1D grid NE*MTILES*(DF/BN)=6144; XCD-chunked swizzle, mt fastest within chunk.

__global__ __launch_bounds__(256)
void k_mm1(const unsigned short* __restrict__ Xg, const unsigned short* __restrict__ W1T,
           const float* __restrict__ b1, const int* __restrict__ counts,
           const int* __restrict__ offsets, unsigned short* __restrict__ H) {
    const int TOT = NE * MTILES * (DF / BN);                 // 6144
    int work = (blockIdx.x & 7) * (TOT >> 3) + (blockIdx.x >> 3);
    const int mt = work % MTILES;
    const int en = work / MTILES;
    const int e  = en >> 5;                                  // / (DF/BN)=32
    const int n0 = (en & 31) * BN;
    const int ne = counts[e];
    const int m0 = mt * BM;
    if (m0 >= ne) return;
    const int rows = min(BM, ne - m0);
    const int slotbase = offsets[e] + m0;

    __shared__ unsigned short As[2][BM * BK];   // linear [row][k]
    __shared__ unsigned short Bs[2][BN * BK];

    const int tid  = threadIdx.x;
    const int lane = tid & 63;
    const int w    = tid >> 6;
    const int wm   = w >> 1, wn = w & 1;

    const unsigned short* bte = W1T + (size_t)e * (size_t)DF * DM;
    const int arow = (lane >> 3);
    const int kofs = (lane & 7) * 8;

    f32x4 acc[4][4];
#pragma unroll
    for (int a = 0; a < 4; a++)
#pragma unroll
        for (int b = 0; b < 4; b++) acc[a][b] = (f32x4)0.f;

    auto stage = [&](int buf, int k0) {
#pragma unroll
        for (int q = 0; q < 4; q++) {
            int row = (w * 4 + q) * 8 + arow;
            GLL(Xg + (size_t)(slotbase + row) * DM + k0 + kofs,
                &As[buf][(w * 4 + q) * 512]);
            GLL(bte + (size_t)(n0 + row) * DM + k0 + kofs,
                &Bs[buf][(w * 4 + q) * 512]);
        }
    };

    stage(0, 0);
    __syncthreads();
    int cur = 0;
#pragma unroll 1
    for (int kt = 0; kt < NK1; ++kt) {
        if (kt + 1 < NK1) stage(cur ^ 1, (kt + 1) * BK);
#pragma unroll
        for (int ks = 0; ks < 2; ks++) {
            const int ko = ks * 32 + (lane >> 4) * 8;
            s16x8 af[4], bfr[4];
#pragma unroll
            for (int f = 0; f < 4; f++)
                af[f] = *(const s16x8*)&As[cur][(wm * 64 + f * 16 + (lane & 15)) * BK + ko];
#pragma unroll
            for (int f = 0; f < 4; f++)
                bfr[f] = *(const s16x8*)&Bs[cur][(wn * 64 + f * 16 + (lane & 15)) * BK + ko];
#pragma unroll
            for (int fm = 0; fm < 4; fm++)
#pragma unroll
                for (int fn = 0; fn < 4; fn++)
                    acc[fm][fn] = __builtin_amdgcn_mfma_f32_16x16x32_bf16(
                        af[fm], bfr[fn], acc[fm][fn], 0, 0, 0);
        }
        __syncthreads();
        cur ^= 1;
    }

    const float* b1e = b1 + (size_t)e * DF;
#pragma unroll
    for (int fm = 0; fm < 4; fm++) {
        const int mrow = wm * 64 + fm * 16 + ((lane >> 4) << 2);
#pragma unroll
        for (int fn = 0; fn < 4; fn++) {
            const int ncol = n0 + wn * 64 + fn * 16 + (lane & 15);
            const float bb = b1e[ncol];
#pragma unroll
            for (int r = 0; r < 4; r++) {
                const int m = mrow + r;
                if (m < rows) {
                    float h = acc[fm][fn][r] + bb;
                    h = 0.5f * h * (1.f + erff(h * 0.70710678118654752f));
                    H[(size_t)(slotbase + m) * DF + ncol] = f2bf(h);
                }
            }
        }
    }
}

// ---------------- MM2: Y = H @ W2T^T  [global_load_lds, dbuf] ----------------
// 1D grid NE*MTILES*(DM/BN)=1536; same swizzle scheme.

__global__ __launch_bounds__(256)
void k_mm2(const unsigned short* __restrict__ Hb, const unsigned short* __restrict__ W2T,
           const int* __restrict__ counts, const int* __restrict__ offsets,
           float* __restrict__ Y) {
    const int TOT = NE * MTILES * (DM / BN);                 // 1536
    int work = (blockIdx.x & 7) * (TOT >> 3) + (blockIdx.x >> 3);
    const int mt = work % MTILES;
    const int en = work / MTILES;
    const int e  = en >> 3;                                  // / (DM/BN)=8
    const int n0 = (en & 7) * BN;
    const int ne = counts[e];
    const int m0 = mt * BM;
    if (m0 >= ne) return;
    const int rows = min(BM, ne - m0);
    const int slotbase = offsets[e] + m0;

    __shared__ unsigned short As[2][BM * BK];
    __shared__ unsigned short Bs[2][BN * BK];

    const int tid  = threadIdx.x;
    const int lane = tid & 63;
    const int w    = tid >> 6;
    const int wm   = w >> 1, wn = w & 1;

    const unsigned short* bte = W2T + (size_t)e * (size_t)DF * DM;
    const int arow = (lane >> 3);
    const int kofs = (lane & 7) * 8;

    f32x4 acc[4][4];
#pragma unroll
    for (int a = 0; a < 4; a++)
#pragma unroll
        for (int b = 0; b < 4; b++) acc[a][b] = (f32x4)0.f;

    auto stage = [&](int buf, int k0) {
#pragma unroll
        for (int q = 0; q < 4; q++) {
            int row = (w * 4 + q) * 8 + arow;
            GLL(Hb + (size_t)(slotbase + row) * DF + k0 + kofs,
                &As[buf][(w * 4 + q) * 512]);
            GLL(bte + (size_t)(n0 + row) * DF + k0 + kofs,
                &Bs[buf][(w * 4 + q) * 512]);
        }
    };

    stage(0, 0);
    __syncthreads();
    int cur = 0;
#pragma unroll 1
    for (int kt = 0; kt < NK2; ++kt) {
        if (kt + 1 < NK2) stage(cur ^ 1, (kt + 1) * BK);
#pragma unroll
        for (int ks = 0; ks < 2; ks++) {
            const int ko = ks * 32 + (lane >> 4) * 8;
            s16x8 af[4], bfr[4];
#pragma unroll
            for (int f = 0; f < 4; f++)
                af[f] = *(const s16x8*)&As[cur][(wm * 64 + f * 16 + (lane & 15)) * BK + ko];
#pragma unroll
            for (int f = 0; f < 4; f++)
                bfr[f] = *(const s16x8*)&Bs[cur][(wn * 64 + f * 16 + (lane & 15)) * BK + ko];
#pragma unroll
            for (int fm = 0; fm < 4; fm++)
#pragma unroll
                for (int fn = 0; fn < 4; fn++)
                    acc[fm][fn] = __builtin_amdgcn_mfma_f32_16x16x32_bf16(
                        af[fm], bfr[fn], acc[fm][fn], 0, 0, 0);
        }
        __syncthreads();
        cur ^= 1;
    }

#pragma unroll
    for (int fm = 0; fm < 4; fm++) {
        const int mrow = wm * 64 + fm * 16 + ((lane >> 4) << 2);
#pragma unroll
        for (int fn = 0; fn < 4; fn++) {
            const int ncol = n0 + wn * 64 + fn * 16 + (lane & 15);
#pragma unroll
            for (int r = 0; r < 4; r++) {
                const int m = mrow + r;
                if (m < rows)
                    Y[(size_t)(slotbase + m) * DM + ncol] = acc[fm][fn][r];
            }
        }
    }
}

// ---------------- launch ----------------

extern "C" void kernel_launch(void* const* d_in, const int* in_sizes, int n_in,
                              void* d_out, int out_size, void* d_ws, size_t ws_size,
                              hipStream_t stream) {
    const float* x   = (const float*)d_in[0];
    const float* gw  = (const float*)d_in[1];
    const float* gb  = (const float*)d_in[2];
    const float* w1  = (const float*)d_in[3];
    const float* b1  = (const float*)d_in[4];
    const float* w2  = (const float*)d_in[5];
    const float* b2  = (const float*)d_in[6];
    float* out = (float*)d_out;

    size_t off = 0;
    auto alloc = [&](size_t bytes) {
        void* p = (char*)d_ws + off;
        off += (bytes + 255) & ~(size_t)255;
        return p;
    };
    float* gwT       = (float*)alloc(NE * DM * sizeof(float));
    int*   idx       = (int*)alloc(T2 * sizeof(int));
    float* prob      = (float*)alloc(T2 * sizeof(float));
    int*   counts    = (int*)alloc(32 * sizeof(int));
    int*   offsets   = (int*)alloc(32 * sizeof(int));
    int*   slot_tok  = (int*)alloc(T2 * sizeof(int));
    int*   pair_slot = (int*)alloc(T2 * sizeof(int));
    unsigned short* Xg = (unsigned short*)alloc((size_t)(T2 + BM) * DM * sizeof(unsigned short));
    unsigned short* Hb = (unsigned short*)alloc((size_t)(T2 + BM) * DF * sizeof(unsigned short));
    float* Yb        = (float*)alloc((size_t)(T2 + BM) * DM * sizeof(float));
    unsigned short* W1T = (unsigned short*)alloc((size_t)NE * DM * DF * sizeof(unsigned short));
    unsigned short* W2T = (unsigned short*)alloc((size_t)NE * DF * DM * sizeof(unsigned short));
    // total ~523 MB; measured ws_size ~1.61 GB (R5 fillBuffer evidence)

    k_transpose_gw<<<NE, 256, 0, stream>>>(gw, gwT);
    k_gate<<<T_TOK / 4, 256, 0, stream>>>(x, gwT, gb, idx, prob);
    k_route<<<1, 1024, 0, stream>>>(idx, counts, offsets, slot_tok, pair_slot);
    k_gather<<<T2, 256, 0, stream>>>(x, slot_tok, Xg);

    dim3 gc(1024, NE * 2);
    k_conv<<<gc, 256, 0, stream>>>(w1, w2, W1T, W2T);

    k_mm1<<<NE * MTILES * (DF / BN), 256, 0, stream>>>(Xg, W1T, b1, counts, offsets, Hb);
    k_mm2<<<NE * MTILES * (DM / BN), 256, 0, stream>>>(Hb, W2T, counts, offsets, Yb);
    k_combine<<<T_TOK, 256, 0, stream>>>(Yb, pair_slot, prob, idx, b2, out);
}

// Round 8
// 712.934 us; speedup vs baseline: 1.0561x; 1.0561x over previous
//
#include <hip/hip_runtime.h>
#include <math.h>

#define DM 1024
#define DF 4096
#define NE 24
#define T_TOK 4096
#define T2 (T_TOK*2)

#define BM 128
#define BN 128
#define BK 64
#define MTILES 8
#define NK1 (DM / BK)   // 16
#define NK2 (DF / BK)   // 64

typedef __attribute__((ext_vector_type(4))) float f32x4;
typedef __attribute__((ext_vector_type(8))) short s16x8;

// exact RNE fp32 -> bf16 (finite inputs)
static __device__ __forceinline__ unsigned short f2bf(float f) {
    unsigned int u = __float_as_uint(f);
    unsigned int r = u + 0x7fffu + ((u >> 16) & 1u);
    return (unsigned short)(r >> 16);
}

// async global->LDS, 16B per lane; lds dest is wave-uniform base + lane*16
#define GLL(gsrc, ldst)                                                          \
    __builtin_amdgcn_global_load_lds(                                            \
        (const __attribute__((address_space(1))) void*)(gsrc),                   \
        (__attribute__((address_space(3))) void*)(ldst), 16, 0, 0)

// ---------------- gating ----------------

__global__ void k_transpose_gw(const float* __restrict__ gw, float* __restrict__ gwT) {
    int e = blockIdx.x;
    for (int d = threadIdx.x; d < DM; d += blockDim.x)
        gwT[e * DM + d] = gw[d * NE + e];
}

__global__ void k_gate(const float* __restrict__ x, const float* __restrict__ gwT,
                       const float* __restrict__ gb,
                       int* __restrict__ idx, float* __restrict__ prob) {
    int wave = threadIdx.x >> 6;
    int lane = threadIdx.x & 63;
    int t = blockIdx.x * 4 + wave;
    if (t >= T_TOK) return;
    const float* xr = x + (size_t)t * DM;
    float acc[NE];
#pragma unroll
    for (int e = 0; e < NE; e++) acc[e] = 0.f;
    for (int i = 0; i < DM / 64; i++) {
        int d = lane + i * 64;
        float xv = xr[d];
#pragma unroll
        for (int e = 0; e < NE; e++) acc[e] = fmaf(xv, gwT[e * DM + d], acc[e]);
    }
#pragma unroll
    for (int e = 0; e < NE; e++) {
        float v = acc[e];
        for (int off = 32; off >= 1; off >>= 1) v += __shfl_xor(v, off);
        acc[e] = v;
    }
    if (lane == 0) {
        float v1 = -1e30f, v2 = -1e30f;
        int i1 = -1, i2 = -1;
        for (int e = 0; e < NE; e++) {
            float s = acc[e] + gb[e];
            if (s > v1) { v2 = v1; i2 = i1; v1 = s; i1 = e; }
            else if (s > v2) { v2 = s; i2 = e; }
        }
        float e2 = expf(v2 - v1);
        float inv = 1.f / (1.f + e2);
        idx[t * 2] = i1; idx[t * 2 + 1] = i2;
        prob[t * 2] = inv; prob[t * 2 + 1] = e2 * inv;
    }
}

// ---------------- routing: count + scan + scatter in one block ----------------

__global__ __launch_bounds__(1024)
void k_route(const int* __restrict__ idx, int* __restrict__ counts,
             int* __restrict__ offsets, int* __restrict__ slot_tok,
             int* __restrict__ pair_slot) {
    __shared__ int cnt[NE], offs[NE], cur[NE];
    const int tid = threadIdx.x;
    if (tid < NE) cnt[tid] = 0;
    __syncthreads();
    for (int i = tid; i < T2; i += 1024) atomicAdd(&cnt[idx[i]], 1);
    __syncthreads();
    if (tid == 0) {
        int s = 0;
        for (int e = 0; e < NE; e++) {
            offs[e] = s; offsets[e] = s; counts[e] = cnt[e]; s += cnt[e];
        }
    }
    if (tid < NE) cur[tid] = 0;
    __syncthreads();
    for (int i = tid; i < T2; i += 1024) {
        int e = idx[i];
        int pos = offs[e] + atomicAdd(&cur[e], 1);
        slot_tok[pos] = i >> 1;
        pair_slot[i] = pos;
    }
}

// gather routed token rows into dense bf16 slot-major matrix Xg[slot][DM]
__global__ void k_gather(const float* __restrict__ x, const int* __restrict__ slot_tok,
                         unsigned short* __restrict__ Xg) {
    int s = blockIdx.x;
    int tok = slot_tok[s];
    const float4* src = (const float4*)(x + (size_t)tok * DM);
    ushort4* dst = (ushort4*)(Xg + (size_t)s * DM);
    for (int i = threadIdx.x; i < DM / 4; i += blockDim.x) {
        float4 v = src[i];
        ushort4 o;
        o.x = f2bf(v.x); o.y = f2bf(v.y); o.z = f2bf(v.z); o.w = f2bf(v.w);
        dst[i] = o;
    }
}

// out[t] = p1*(Y[s1]+b2[e1]) + p2*(Y[s2]+b2[e2])
__global__ void k_combine(const float* __restrict__ Y, const int* __restrict__ pair_slot,
                          const float* __restrict__ prob, const int* __restrict__ idx,
                          const float* __restrict__ b2, float* __restrict__ out) {
    int t = blockIdx.x;
    int s1 = pair_slot[t * 2], s2 = pair_slot[t * 2 + 1];
    int e1 = idx[t * 2], e2 = idx[t * 2 + 1];
    float p1 = prob[t * 2], p2 = prob[t * 2 + 1];
    const float4* y1 = (const float4*)(Y + (size_t)s1 * DM);
    const float4* y2 = (const float4*)(Y + (size_t)s2 * DM);
    const float4* ba = (const float4*)(b2 + (size_t)e1 * DM);
    const float4* bb = (const float4*)(b2 + (size_t)e2 * DM);
    float4* o = (float4*)(out + (size_t)t * DM);
    int i = threadIdx.x;
    float4 a = y1[i], b = y2[i], c = ba[i], d = bb[i];
    float4 r;
    r.x = p1 * (a.x + c.x) + p2 * (b.x + d.x);
    r.y = p1 * (a.y + c.y) + p2 * (b.y + d.y);
    r.z = p1 * (a.z + c.z) + p2 * (b.z + d.z);
    r.w = p1 * (a.w + c.w) + p2 * (b.w + d.w);
    o[i] = r;
}

// ---------------- transpose+convert: W[K][N] fp32 -> WT[N][K] bf16 ----------------
// grid (N/64, K/64, NE); 16B/lane stores, 128B per 4-lane group.

__global__ __launch_bounds__(256)
void k_convT(const float* __restrict__ W, unsigned short* __restrict__ WT,
             int K, int N) {
    const int e = blockIdx.z;
    const int n0 = blockIdx.x * 64, k0 = blockIdx.y * 64;
    W += (size_t)e * K * N;
    WT += (size_t)e * K * N;
    __shared__ float T[64][65];
    const int t = threadIdx.x;
    const int rr = t >> 4, cc = (t & 15) * 4;
#pragma unroll
    for (int p = 0; p < 4; p++) {
        float4 v = *(const float4*)(W + (size_t)(k0 + rr + p * 16) * N + n0 + cc);
        T[rr + p * 16][cc + 0] = v.x;
        T[rr + p * 16][cc + 1] = v.y;
        T[rr + p * 16][cc + 2] = v.z;
        T[rr + p * 16][cc + 3] = v.w;
    }
    __syncthreads();
    const int n = t >> 2, kb = (t & 3) * 16;
#pragma unroll
    for (int p = 0; p < 2; p++) {
        s16x8 o;
#pragma unroll
        for (int j = 0; j < 8; j++)
            o[j] = (short)f2bf(T[kb + p * 8 + j][n]);
        *(s16x8*)(WT + (size_t)(n0 + n) * K + k0 + kb + p * 8) = o;
    }
}

// ---------------- MM kernels: m97 single-buffer + T2 involution swizzle ----------
// LDS linear [row][BK], 128B rows. Stage: global chunk (lane&7)^(lane>>3) so that
// LDS[row][slot] holds chunk slot^(row&7); read XORs the same key -> 2-way banks.

__global__ __launch_bounds__(256)
void k_mm1(const unsigned short* __restrict__ Xg, const unsigned short* __restrict__ W1T,
           const float* __restrict__ b1, const int* __restrict__ counts,
           const int* __restrict__ offsets, unsigned short* __restrict__ H) {
    const int TOT = NE * MTILES * (DF / BN);                 // 6144
    int work = (blockIdx.x & 7) * (TOT >> 3) + (blockIdx.x >> 3);
    const int mt = work % MTILES;
    const int en = work / MTILES;
    const int e  = en >> 5;
    const int n0 = (en & 31) * BN;
    const int ne = counts[e];
    const int m0 = mt * BM;
    if (m0 >= ne) return;
    const int rows = min(BM, ne - m0);
    const int slotbase = offsets[e] + m0;

    __shared__ unsigned short As[BM * BK];   // 16 KB
    __shared__ unsigned short Bs[BN * BK];   // 16 KB

    const int tid  = threadIdx.x;
    const int lane = tid & 63;
    const int w    = tid >> 6;
    const int wm   = w >> 1, wn = w & 1;

    const unsigned short* bte = W1T + (size_t)e * (size_t)DF * DM;
    const int arow = lane >> 3;                    // row within 8-row group
    const int gchunk = ((lane & 7) ^ arow) * 8;    // pre-swizzled global chunk (elems)

    f32x4 acc[4][4];
#pragma unroll
    for (int a = 0; a < 4; a++)
#pragma unroll
        for (int b = 0; b < 4; b++) acc[a][b] = (f32x4)0.f;

#pragma unroll 1
    for (int kt = 0; kt < NK1; ++kt) {
        const int k0 = kt * BK;
#pragma unroll
        for (int q = 0; q < 4; q++) {
            int row = (w * 4 + q) * 8 + arow;
            GLL(Xg + (size_t)(slotbase + row) * DM + k0 + gchunk,
                &As[(w * 4 + q) * 512]);
            GLL(bte + (size_t)(n0 + row) * DM + k0 + gchunk,
                &Bs[(w * 4 + q) * 512]);
        }
        __syncthreads();
#pragma unroll
        for (int ks = 0; ks < 2; ks++) {
            s16x8 af[4], bfr[4];
#pragma unroll
            for (int f = 0; f < 4; f++) {
                int r = wm * 64 + f * 16 + (lane & 15);
                af[f] = *(const s16x8*)((const char*)As + r * 128 +
                         ((((ks << 2) | (lane >> 4)) ^ (lane & 7)) << 4));
            }
#pragma unroll
            for (int f = 0; f < 4; f++) {
                int r = wn * 64 + f * 16 + (lane & 15);
                bfr[f] = *(const s16x8*)((const char*)Bs + r * 128 +
                          ((((ks << 2) | (lane >> 4)) ^ (lane & 7)) << 4));
            }
#pragma unroll
            for (int fm = 0; fm < 4; fm++)
#pragma unroll
                for (int fn = 0; fn < 4; fn++)
                    acc[fm][fn] = __builtin_amdgcn_mfma_f32_16x16x32_bf16(
                        af[fm], bfr[fn], acc[fm][fn], 0, 0, 0);
        }
        __syncthreads();
    }

    const float* b1e = b1 + (size_t)e * DF;
#pragma unroll
    for (int fm = 0; fm < 4; fm++) {
        const int mrow = wm * 64 + fm * 16 + ((lane >> 4) << 2);
#pragma unroll
        for (int fn = 0; fn < 4; fn++) {
            const int ncol = n0 + wn * 64 + fn * 16 + (lane & 15);
            const float bb = b1e[ncol];
#pragma unroll
            for (int r = 0; r < 4; r++) {
                const int m = mrow + r;
                if (m < rows) {
                    float h = acc[fm][fn][r] + bb;
                    h = 0.5f * h * (1.f + erff(h * 0.70710678118654752f));
                    H[(size_t)(slotbase + m) * DF + ncol] = f2bf(h);
                }
            }
        }
    }
}

__global__ __launch_bounds__(256)
void k_mm2(const unsigned short* __restrict__ Hb, const unsigned short* __restrict__ W2T,
           const int* __restrict__ counts, const int* __restrict__ offsets,
           float* __restrict__ Y) {
    const int TOT = NE * MTILES * (DM / BN);                 // 1536
    int work = (blockIdx.x & 7) * (TOT >> 3) + (blockIdx.x >> 3);
    const int mt = work % MTILES;
    const int en = work / MTILES;
    const int e  = en >> 3;
    const int n0 = (en & 7) * BN;
    const int ne = counts[e];
    const int m0 = mt * BM;
    if (m0 >= ne) return;
    const int rows = min(BM, ne - m0);
    const int slotbase = offsets[e] + m0;

    __shared__ unsigned short As[BM * BK];
    __shared__ unsigned short Bs[BN * BK];

    const int tid  = threadIdx.x;
    const int lane = tid & 63;
    const int w    = tid >> 6;
    const int wm   = w >> 1, wn = w & 1;

    const unsigned short* bte = W2T + (size_t)e * (size_t)DF * DM;
    const int arow = lane >> 3;
    const int gchunk = ((lane & 7) ^ arow) * 8;

    f32x4 acc[4][4];
#pragma unroll
    for (int a = 0; a < 4; a++)
#pragma unroll
        for (int b = 0; b < 4; b++) acc[a][b] = (f32x4)0.f;

#pragma unroll 1
    for (int kt = 0; kt < NK2; ++kt) {
        const int k0 = kt * BK;
#pragma unroll
        for (int q = 0; q < 4; q++) {
            int row = (w * 4 + q) * 8 + arow;
            GLL(Hb + (size_t)(slotbase + row) * DF + k0 + gchunk,
                &As[(w * 4 + q) * 512]);
            GLL(bte + (size_t)(n0 + row) * DF + k0 + gchunk,
                &Bs[(w * 4 + q) * 512]);
        }
        __syncthreads();
#pragma unroll
        for (int ks = 0; ks < 2; ks++) {
            s16x8 af[4], bfr[4];
#pragma unroll
            for (int f = 0; f < 4; f++) {
                int r = wm * 64 + f * 16 + (lane & 15);
                af[f] = *(const s16x8*)((const char*)As + r * 128 +
                         ((((ks << 2) | (lane >> 4)) ^ (lane & 7)) << 4));
            }
#pragma unroll
            for (int f = 0; f < 4; f++) {
                int r = wn * 64 + f * 16 + (lane & 15);
                bfr[f] = *(const s16x8*)((const char*)Bs + r * 128 +
                          ((((ks << 2) | (lane >> 4)) ^ (lane & 7)) << 4));
            }
#pragma unroll
            for (int fm = 0; fm < 4; fm++)
#pragma unroll
                for (int fn = 0; fn < 4; fn++)
                    acc[fm][fn] = __builtin_amdgcn_mfma_f32_16x16x32_bf16(
                        af[fm], bfr[fn], acc[fm][fn], 0, 0, 0);
        }
        __syncthreads();
    }

#pragma unroll
    for (int fm = 0; fm < 4; fm++) {
        const int mrow = wm * 64 + fm * 16 + ((lane >> 4) << 2);
#pragma unroll
        for (int fn = 0; fn < 4; fn++) {
            const int ncol = n0 + wn * 64 + fn * 16 + (lane & 15);
#pragma unroll
            for (int r = 0; r < 4; r++) {
                const int m = mrow + r;
                if (m < rows)
                    Y[(size_t)(slotbase + m) * DM + ncol] = acc[fm][fn][r];
            }
        }
    }
}

// ---------------- launch ----------------

extern "C" void kernel_launch(void* const* d_in, const int* in_sizes, int n_in,
                              void* d_out, int out_size, void* d_ws, size_t ws_size,
                              hipStream_t stream) {
    const float* x   = (const float*)d_in[0];
    const float* gw  = (const float*)d_in[1];
    const float* gb  = (const float*)d_in[2];
    const float* w1  = (const float*)d_in[3];
    const float* b1  = (const float*)d_in[4];
    const float* w2  = (const float*)d_in[5];
    const float* b2  = (const float*)d_in[6];
    float* out = (float*)d_out;

    size_t off = 0;
    auto alloc = [&](size_t bytes) {
        void* p = (char*)d_ws + off;
        off += (bytes + 255) & ~(size_t)255;
        return p;
    };
    float* gwT       = (float*)alloc(NE * DM * sizeof(float));
    int*   idx       = (int*)alloc(T2 * sizeof(int));
    float* prob      = (float*)alloc(T2 * sizeof(float));
    int*   counts    = (int*)alloc(32 * sizeof(int));
    int*   offsets   = (int*)alloc(32 * sizeof(int));
    int*   slot_tok  = (int*)alloc(T2 * sizeof(int));
    int*   pair_slot = (int*)alloc(T2 * sizeof(int));
    unsigned short* Xg = (unsigned short*)alloc((size_t)(T2 + BM) * DM * sizeof(unsigned short));
    unsigned short* Hb = (unsigned short*)alloc((size_t)(T2 + BM) * DF * sizeof(unsigned short));
    float* Yb        = (float*)alloc((size_t)(T2 + BM) * DM * sizeof(float));
    unsigned short* W1T = (unsigned short*)alloc((size_t)NE * DM * DF * sizeof(unsigned short));
    unsigned short* W2T = (unsigned short*)alloc((size_t)NE * DF * DM * sizeof(unsigned short));
    // ~523 MB total; ws_size ~1.61 GB (R5 fillBuffer evidence)

    k_transpose_gw<<<NE, 256, 0, stream>>>(gw, gwT);
    k_gate<<<T_TOK / 4, 256, 0, stream>>>(x, gwT, gb, idx, prob);
    k_route<<<1, 1024, 0, stream>>>(idx, counts, offsets, slot_tok, pair_slot);
    k_gather<<<T2, 256, 0, stream>>>(x, slot_tok, Xg);

    // convT(W1) -> mm1 -> convT(W2) -> mm2: each WT is L3-hot when consumed
    dim3 gc1(DF / 64, DM / 64, NE);
    k_convT<<<gc1, 256, 0, stream>>>(w1, W1T, DM, DF);
    k_mm1<<<NE * MTILES * (DF / BN), 256, 0, stream>>>(Xg, W1T, b1, counts, offsets, Hb);

    dim3 gc2(DM / 64, DF / 64, NE);
    k_convT<<<gc2, 256, 0, stream>>>(w2, W2T, DF, DM);
    k_mm2<<<NE * MTILES * (DM / BN), 256, 0, stream>>>(Hb, W2T, counts, offsets, Yb);

    k_combine<<<T_TOK, 256, 0, stream>>>(Yb, pair_slot, prob, idx, b2, out);
}

// Round 11
// 701.229 us; speedup vs baseline: 1.0737x; 1.0167x over previous
//
#include <hip/hip_runtime.h>
#include <math.h>

#define DM 1024
#define DF 4096
#define NE 24
#define T_TOK 4096
#define T2 (T_TOK*2)

#define BM 128
#define BN 128
#define BK 64
#define MTILES 8
#define NK1 (DM / BK)   // 16
#define NK2 (DF / BK)   // 64

typedef __attribute__((ext_vector_type(4))) float f32x4;
typedef __attribute__((ext_vector_type(8))) short s16x8;

// exact RNE fp32 -> bf16 (finite inputs)
static __device__ __forceinline__ unsigned short f2bf(float f) {
    unsigned int u = __float_as_uint(f);
    unsigned int r = u + 0x7fffu + ((u >> 16) & 1u);
    return (unsigned short)(r >> 16);
}

// async global->LDS, 16B per lane; lds dest is wave-uniform base + lane*16
#define GLL(gsrc, ldst)                                                          \
    __builtin_amdgcn_global_load_lds(                                            \
        (const __attribute__((address_space(1))) void*)(gsrc),                   \
        (__attribute__((address_space(3))) void*)(ldst), 16, 0, 0)

// ---------------- gating ----------------

__global__ void k_transpose_gw(const float* __restrict__ gw, float* __restrict__ gwT) {
    int e = blockIdx.x;
    for (int d = threadIdx.x; d < DM; d += blockDim.x)
        gwT[e * DM + d] = gw[d * NE + e];
}

__global__ void k_gate(const float* __restrict__ x, const float* __restrict__ gwT,
                       const float* __restrict__ gb,
                       int* __restrict__ idx, float* __restrict__ prob) {
    int wave = threadIdx.x >> 6;
    int lane = threadIdx.x & 63;
    int t = blockIdx.x * 4 + wave;
    if (t >= T_TOK) return;
    const float* xr = x + (size_t)t * DM;
    float acc[NE];
#pragma unroll
    for (int e = 0; e < NE; e++) acc[e] = 0.f;
    for (int i = 0; i < DM / 64; i++) {
        int d = lane + i * 64;
        float xv = xr[d];
#pragma unroll
        for (int e = 0; e < NE; e++) acc[e] = fmaf(xv, gwT[e * DM + d], acc[e]);
    }
#pragma unroll
    for (int e = 0; e < NE; e++) {
        float v = acc[e];
        for (int off = 32; off >= 1; off >>= 1) v += __shfl_xor(v, off);
        acc[e] = v;
    }
    if (lane == 0) {
        float v1 = -1e30f, v2 = -1e30f;
        int i1 = -1, i2 = -1;
        for (int e = 0; e < NE; e++) {
            float s = acc[e] + gb[e];
            if (s > v1) { v2 = v1; i2 = i1; v1 = s; i1 = e; }
            else if (s > v2) { v2 = s; i2 = e; }
        }
        float e2 = expf(v2 - v1);
        float inv = 1.f / (1.f + e2);
        idx[t * 2] = i1; idx[t * 2 + 1] = i2;
        prob[t * 2] = inv; prob[t * 2 + 1] = e2 * inv;
    }
}

// ---------------- routing: count + scan + scatter in one block ----------------

__global__ __launch_bounds__(1024)
void k_route(const int* __restrict__ idx, int* __restrict__ counts,
             int* __restrict__ offsets, int* __restrict__ slot_tok,
             int* __restrict__ pair_slot) {
    __shared__ int cnt[NE], offs[NE], cur[NE];
    const int tid = threadIdx.x;
    if (tid < NE) cnt[tid] = 0;
    __syncthreads();
    for (int i = tid; i < T2; i += 1024) atomicAdd(&cnt[idx[i]], 1);
    __syncthreads();
    if (tid == 0) {
        int s = 0;
        for (int e = 0; e < NE; e++) {
            offs[e] = s; offsets[e] = s; counts[e] = cnt[e]; s += cnt[e];
        }
    }
    if (tid < NE) cur[tid] = 0;
    __syncthreads();
    for (int i = tid; i < T2; i += 1024) {
        int e = idx[i];
        int pos = offs[e] + atomicAdd(&cur[e], 1);
        slot_tok[pos] = i >> 1;
        pair_slot[i] = pos;
    }
}

// gather routed token rows into dense bf16 slot-major matrix Xg[slot][DM]
__global__ void k_gather(const float* __restrict__ x, const int* __restrict__ slot_tok,
                         unsigned short* __restrict__ Xg) {
    int s = blockIdx.x;
    int tok = slot_tok[s];
    const float4* src = (const float4*)(x + (size_t)tok * DM);
    ushort4* dst = (ushort4*)(Xg + (size_t)s * DM);
    for (int i = threadIdx.x; i < DM / 4; i += blockDim.x) {
        float4 v = src[i];
        ushort4 o;
        o.x = f2bf(v.x); o.y = f2bf(v.y); o.z = f2bf(v.z); o.w = f2bf(v.w);
        dst[i] = o;
    }
}

// out[t] = p1*(Y[s1]+b2[e1]) + p2*(Y[s2]+b2[e2])
__global__ void k_combine(const float* __restrict__ Y, const int* __restrict__ pair_slot,
                          const float* __restrict__ prob, const int* __restrict__ idx,
                          const float* __restrict__ b2, float* __restrict__ out) {
    int t = blockIdx.x;
    int s1 = pair_slot[t * 2], s2 = pair_slot[t * 2 + 1];
    int e1 = idx[t * 2], e2 = idx[t * 2 + 1];
    float p1 = prob[t * 2], p2 = prob[t * 2 + 1];
    const float4* y1 = (const float4*)(Y + (size_t)s1 * DM);
    const float4* y2 = (const float4*)(Y + (size_t)s2 * DM);
    const float4* ba = (const float4*)(b2 + (size_t)e1 * DM);
    const float4* bb = (const float4*)(b2 + (size_t)e2 * DM);
    float4* o = (float4*)(out + (size_t)t * DM);
    int i = threadIdx.x;
    float4 a = y1[i], b = y2[i], c = ba[i], d = bb[i];
    float4 r;
    r.x = p1 * (a.x + c.x) + p2 * (b.x + d.x);
    r.y = p1 * (a.y + c.y) + p2 * (b.y + d.y);
    r.z = p1 * (a.z + c.z) + p2 * (b.z + d.z);
    r.w = p1 * (a.w + c.w) + p2 * (b.w + d.w);
    o[i] = r;
}

// ---------------- transpose+convert: W[K][N] fp32 -> WT[N][K] bf16 ----------------
// grid (N/64, K/64, NE); 16B/lane stores, 128B per 4-lane group.

__global__ __launch_bounds__(256)
void k_convT(const float* __restrict__ W, unsigned short* __restrict__ WT,
             int K, int N) {
    const int e = blockIdx.z;
    const int n0 = blockIdx.x * 64, k0 = blockIdx.y * 64;
    W += (size_t)e * K * N;
    WT += (size_t)e * K * N;
    __shared__ float T[64][65];
    const int t = threadIdx.x;
    const int rr = t >> 4, cc = (t & 15) * 4;
#pragma unroll
    for (int p = 0; p < 4; p++) {
        float4 v = *(const float4*)(W + (size_t)(k0 + rr + p * 16) * N + n0 + cc);
        T[rr + p * 16][cc + 0] = v.x;
        T[rr + p * 16][cc + 1] = v.y;
        T[rr + p * 16][cc + 2] = v.z;
        T[rr + p * 16][cc + 3] = v.w;
    }
    __syncthreads();
    const int n = t >> 2, kb = (t & 3) * 16;
#pragma unroll
    for (int p = 0; p < 2; p++) {
        s16x8 o;
#pragma unroll
        for (int j = 0; j < 8; j++)
            o[j] = (short)f2bf(T[kb + p * 8 + j][n]);
        *(s16x8*)(WT + (size_t)(n0 + n) * K + k0 + kb + p * 8) = o;
    }
}

// ---------------- MM kernels: T3/T4 counted-vmcnt 2-deep GLL pipeline ------------
// LDS linear [row][BK] 128B rows, dbuf. Involution swizzle (R8, conflicts==0):
// stage global chunk (lane&7)^(lane>>3); read XORs same key.
// Schedule per K-step: vmcnt(8) -> barrier -> ds_read+MFMA -> barrier -> stage(kt+2).
// vmcnt never drains to 0 in steady state (8 newer loads stay in flight).

__global__ __launch_bounds__(256)
void k_mm1(const unsigned short* __restrict__ Xg, const unsigned short* __restrict__ W1T,
           const float* __restrict__ b1, const int* __restrict__ counts,
           const int* __restrict__ offsets, unsigned short* __restrict__ H) {
    const int TOT = NE * MTILES * (DF / BN);                 // 6144
    int work = (blockIdx.x & 7) * (TOT >> 3) + (blockIdx.x >> 3);
    const int mt = work % MTILES;
    const int en = work / MTILES;
    const int e  = en >> 5;
    const int n0 = (en & 31) * BN;
    const int ne = counts[e];
    const int m0 = mt * BM;
    if (m0 >= ne) return;
    const int rows = min(BM, ne - m0);
    const int slotbase = offsets[e] + m0;

    __shared__ unsigned short As[2][BM * BK];   // 2 x 16 KB
    __shared__ unsigned short Bs[2][BN * BK];   // 2 x 16 KB

    const int tid  = threadIdx.x;
    const int lane = tid & 63;
    const int w    = tid >> 6;
    const int wm   = w >> 1, wn = w & 1;

    const unsigned short* bte = W1T + (size_t)e * (size_t)DF * DM;
    const int arow = lane >> 3;                    // row within 8-row group
    const int gchunk = ((lane & 7) ^ arow) * 8;    // pre-swizzled global chunk (elems)

    f32x4 acc[4][4];
#pragma unroll
    for (int a = 0; a < 4; a++)
#pragma unroll
        for (int b = 0; b < 4; b++) acc[a][b] = (f32x4)0.f;

    auto stage = [&](int buf, int k0) {
#pragma unroll
        for (int q = 0; q < 4; q++) {
            int row = (w * 4 + q) * 8 + arow;
            GLL(Xg + (size_t)(slotbase + row) * DM + k0 + gchunk,
                &As[buf][(w * 4 + q) * 512]);
            GLL(bte + (size_t)(n0 + row) * DM + k0 + gchunk,
                &Bs[buf][(w * 4 + q) * 512]);
        }
    };

    stage(0, 0);
    stage(1, BK);
    int cur = 0;
#pragma unroll 1
    for (int kt = 0; kt < NK1; ++kt) {
        if (kt + 2 < NK1) asm volatile("s_waitcnt vmcnt(8)" ::: "memory");
        else              asm volatile("s_waitcnt vmcnt(0)" ::: "memory");
        __builtin_amdgcn_s_barrier();
        __builtin_amdgcn_sched_barrier(0);
#pragma unroll
        for (int ks = 0; ks < 2; ks++) {
            s16x8 af[4], bfr[4];
#pragma unroll
            for (int f = 0; f < 4; f++) {
                int r = wm * 64 + f * 16 + (lane & 15);
                af[f] = *(const s16x8*)((const char*)As[cur] + r * 128 +
                         ((((ks << 2) | (lane >> 4)) ^ (lane & 7)) << 4));
            }
#pragma unroll
            for (int f = 0; f < 4; f++) {
                int r = wn * 64 + f * 16 + (lane & 15);
                bfr[f] = *(const s16x8*)((const char*)Bs[cur] + r * 128 +
                          ((((ks << 2) | (lane >> 4)) ^ (lane & 7)) << 4));
            }
            __builtin_amdgcn_s_setprio(1);
#pragma unroll
            for (int fm = 0; fm < 4; fm++)
#pragma unroll
                for (int fn = 0; fn < 4; fn++)
                    acc[fm][fn] = __builtin_amdgcn_mfma_f32_16x16x32_bf16(
                        af[fm], bfr[fn], acc[fm][fn], 0, 0, 0);
            __builtin_amdgcn_s_setprio(0);
        }
        __builtin_amdgcn_s_barrier();
        __builtin_amdgcn_sched_barrier(0);
        if (kt + 2 < NK1) stage(cur, (kt + 2) * BK);
        cur ^= 1;
    }

    const float* b1e = b1 + (size_t)e * DF;
#pragma unroll
    for (int fm = 0; fm < 4; fm++) {
        const int mrow = wm * 64 + fm * 16 + ((lane >> 4) << 2);
#pragma unroll
        for (int fn = 0; fn < 4; fn++) {
            const int ncol = n0 + wn * 64 + fn * 16 + (lane & 15);
            const float bb = b1e[ncol];
#pragma unroll
            for (int r = 0; r < 4; r++) {
                const int m = mrow + r;
                if (m < rows) {
                    float h = acc[fm][fn][r] + bb;
                    h = 0.5f * h * (1.f + erff(h * 0.70710678118654752f));
                    H[(size_t)(slotbase + m) * DF + ncol] = f2bf(h);
                }
            }
        }
    }
}

__global__ __launch_bounds__(256)
void k_mm2(const unsigned short* __restrict__ Hb, const unsigned short* __restrict__ W2T,
           const int* __restrict__ counts, const int* __restrict__ offsets,
           float* __restrict__ Y) {
    const int TOT = NE * MTILES * (DM / BN);                 // 1536
    int work = (blockIdx.x & 7) * (TOT >> 3) + (blockIdx.x >> 3);
    const int mt = work % MTILES;
    const int en = work / MTILES;
    const int e  = en >> 3;
    const int n0 = (en & 7) * BN;
    const int ne = counts[e];
    const int m0 = mt * BM;
    if (m0 >= ne) return;
    const int rows = min(BM, ne - m0);
    const int slotbase = offsets[e] + m0;

    __shared__ unsigned short As[2][BM * BK];
    __shared__ unsigned short Bs[2][BN * BK];

    const int tid  = threadIdx.x;
    const int lane = tid & 63;
    const int w    = tid >> 6;
    const int wm   = w >> 1, wn = w & 1;

    const unsigned short* bte = W2T + (size_t)e * (size_t)DF * DM;
    const int arow = lane >> 3;
    const int gchunk = ((lane & 7) ^ arow) * 8;

    f32x4 acc[4][4];
#pragma unroll
    for (int a = 0; a < 4; a++)
#pragma unroll
        for (int b = 0; b < 4; b++) acc[a][b] = (f32x4)0.f;

    auto stage = [&](int buf, int k0) {
#pragma unroll
        for (int q = 0; q < 4; q++) {
            int row = (w * 4 + q) * 8 + arow;
            GLL(Hb + (size_t)(slotbase + row) * DF + k0 + gchunk,
                &As[buf][(w * 4 + q) * 512]);
            GLL(bte + (size_t)(n0 + row) * DF + k0 + gchunk,
                &Bs[buf][(w * 4 + q) * 512]);
        }
    };

    stage(0, 0);
    stage(1, BK);
    int cur = 0;
#pragma unroll 1
    for (int kt = 0; kt < NK2; ++kt) {
        if (kt + 2 < NK2) asm volatile("s_waitcnt vmcnt(8)" ::: "memory");
        else              asm volatile("s_waitcnt vmcnt(0)" ::: "memory");
        __builtin_amdgcn_s_barrier();
        __builtin_amdgcn_sched_barrier(0);
#pragma unroll
        for (int ks = 0; ks < 2; ks++) {
            s16x8 af[4], bfr[4];
#pragma unroll
            for (int f = 0; f < 4; f++) {
                int r = wm * 64 + f * 16 + (lane & 15);
                af[f] = *(const s16x8*)((const char*)As[cur] + r * 128 +
                         ((((ks << 2) | (lane >> 4)) ^ (lane & 7)) << 4));
            }
#pragma unroll
            for (int f = 0; f < 4; f++) {
                int r = wn * 64 + f * 16 + (lane & 15);
                bfr[f] = *(const s16x8*)((const char*)Bs[cur] + r * 128 +
                          ((((ks << 2) | (lane >> 4)) ^ (lane & 7)) << 4));
            }
            __builtin_amdgcn_s_setprio(1);
#pragma unroll
            for (int fm = 0; fm < 4; fm++)
#pragma unroll
                for (int fn = 0; fn < 4; fn++)
                    acc[fm][fn] = __builtin_amdgcn_mfma_f32_16x16x32_bf16(
                        af[fm], bfr[fn], acc[fm][fn], 0, 0, 0);
            __builtin_amdgcn_s_setprio(0);
        }
        __builtin_amdgcn_s_barrier();
        __builtin_amdgcn_sched_barrier(0);
        if (kt + 2 < NK2) stage(cur, (kt + 2) * BK);
        cur ^= 1;
    }

#pragma unroll
    for (int fm = 0; fm < 4; fm++) {
        const int mrow = wm * 64 + fm * 16 + ((lane >> 4) << 2);
#pragma unroll
        for (int fn = 0; fn < 4; fn++) {
            const int ncol = n0 + wn * 64 + fn * 16 + (lane & 15);
#pragma unroll
            for (int r = 0; r < 4; r++) {
                const int m = mrow + r;
                if (m < rows)
                    Y[(size_t)(slotbase + m) * DM + ncol] = acc[fm][fn][r];
            }
        }
    }
}

// ---------------- launch ----------------

extern "C" void kernel_launch(void* const* d_in, const int* in_sizes, int n_in,
                              void* d_out, int out_size, void* d_ws, size_t ws_size,
                              hipStream_t stream) {
    const float* x   = (const float*)d_in[0];
    const float* gw  = (const float*)d_in[1];
    const float* gb  = (const float*)d_in[2];
    const float* w1  = (const float*)d_in[3];
    const float* b1  = (const float*)d_in[4];
    const float* w2  = (const float*)d_in[5];
    const float* b2  = (const float*)d_in[6];
    float* out = (float*)d_out;

    size_t off = 0;
    auto alloc = [&](size_t bytes) {
        void* p = (char*)d_ws + off;
        off += (bytes + 255) & ~(size_t)255;
        return p;
    };
    float* gwT       = (float*)alloc(NE * DM * sizeof(float));
    int*   idx       = (int*)alloc(T2 * sizeof(int));
    float* prob      = (float*)alloc(T2 * sizeof(float));
    int*   counts    = (int*)alloc(32 * sizeof(int));
    int*   offsets   = (int*)alloc(32 * sizeof(int));
    int*   slot_tok  = (int*)alloc(T2 * sizeof(int));
    int*   pair_slot = (int*)alloc(T2 * sizeof(int));
    unsigned short* Xg = (unsigned short*)alloc((size_t)(T2 + BM) * DM * sizeof(unsigned short));
    unsigned short* Hb = (unsigned short*)alloc((size_t)(T2 + BM) * DF * sizeof(unsigned short));
    float* Yb        = (float*)alloc((size_t)(T2 + BM) * DM * sizeof(float));
    unsigned short* W1T = (unsigned short*)alloc((size_t)NE * DM * DF * sizeof(unsigned short));
    unsigned short* W2T = (unsigned short*)alloc((size_t)NE * DF * DM * sizeof(unsigned short));
    // ~523 MB total; ws_size ~1.61 GB (R5 fillBuffer evidence)

    k_transpose_gw<<<NE, 256, 0, stream>>>(gw, gwT);
    k_gate<<<T_TOK / 4, 256, 0, stream>>>(x, gwT, gb, idx, prob);
    k_route<<<1, 1024, 0, stream>>>(idx, counts, offsets, slot_tok, pair_slot);
    k_gather<<<T2, 256, 0, stream>>>(x, slot_tok, Xg);

    // convT(W1) -> mm1 -> convT(W2) -> mm2: each WT is L3-hot when consumed
    dim3 gc1(DF / 64, DM / 64, NE);
    k_convT<<<gc1, 256, 0, stream>>>(w1, W1T, DM, DF);
    k_mm1<<<NE * MTILES * (DF / BN), 256, 0, stream>>>(Xg, W1T, b1, counts, offsets, Hb);

    dim3 gc2(DM / 64, DF / 64, NE);
    k_convT<<<gc2, 256, 0, stream>>>(w2, W2T, DF, DM);
    k_mm2<<<NE * MTILES * (DM / BN), 256, 0, stream>>>(Hb, W2T, counts, offsets, Yb);

    k_combine<<<T_TOK, 256, 0, stream>>>(Yb, pair_slot, prob, idx, b2, out);
}

// Round 12
// 672.543 us; speedup vs baseline: 1.1195x; 1.0427x over previous
//
#include <hip/hip_runtime.h>
#include <math.h>

#define DM 1024
#define DF 4096
#define NE 24
#define T_TOK 4096
#define T2 (T_TOK*2)

#define BM 128
#define BN 128
#define BK 64
#define MTILES 8
#define NK1 (DM / BK)   // 16
#define NK2 (DF / BK)   // 64

typedef __attribute__((ext_vector_type(4))) float f32x4;
typedef __attribute__((ext_vector_type(8))) short s16x8;

// exact RNE fp32 -> bf16 (finite inputs)
static __device__ __forceinline__ unsigned short f2bf(float f) {
    unsigned int u = __float_as_uint(f);
    unsigned int r = u + 0x7fffu + ((u >> 16) & 1u);
    return (unsigned short)(r >> 16);
}

// async global->LDS, 16B per lane; lds dest is wave-uniform base + lane*16
#define GLL(gsrc, ldst)                                                          \
    __builtin_amdgcn_global_load_lds(                                            \
        (const __attribute__((address_space(1))) void*)(gsrc),                   \
        (__attribute__((address_space(3))) void*)(ldst), 16, 0, 0)

// ---------------- gating ----------------

__global__ void k_transpose_gw(const float* __restrict__ gw, float* __restrict__ gwT) {
    int e = blockIdx.x;
    for (int d = threadIdx.x; d < DM; d += blockDim.x)
        gwT[e * DM + d] = gw[d * NE + e];
}

__global__ void k_gate(const float* __restrict__ x, const float* __restrict__ gwT,
                       const float* __restrict__ gb,
                       int* __restrict__ idx, float* __restrict__ prob) {
    int wave = threadIdx.x >> 6;
    int lane = threadIdx.x & 63;
    int t = blockIdx.x * 4 + wave;
    if (t >= T_TOK) return;
    const float* xr = x + (size_t)t * DM;
    float acc[NE];
#pragma unroll
    for (int e = 0; e < NE; e++) acc[e] = 0.f;
    for (int i = 0; i < DM / 64; i++) {
        int d = lane + i * 64;
        float xv = xr[d];
#pragma unroll
        for (int e = 0; e < NE; e++) acc[e] = fmaf(xv, gwT[e * DM + d], acc[e]);
    }
#pragma unroll
    for (int e = 0; e < NE; e++) {
        float v = acc[e];
        for (int off = 32; off >= 1; off >>= 1) v += __shfl_xor(v, off);
        acc[e] = v;
    }
    if (lane == 0) {
        float v1 = -1e30f, v2 = -1e30f;
        int i1 = -1, i2 = -1;
        for (int e = 0; e < NE; e++) {
            float s = acc[e] + gb[e];
            if (s > v1) { v2 = v1; i2 = i1; v1 = s; i1 = e; }
            else if (s > v2) { v2 = s; i2 = e; }
        }
        float e2 = expf(v2 - v1);
        float inv = 1.f / (1.f + e2);
        idx[t * 2] = i1; idx[t * 2 + 1] = i2;
        prob[t * 2] = inv; prob[t * 2 + 1] = e2 * inv;
    }
}

// ---------------- routing: count + scan + scatter in one block ----------------

__global__ __launch_bounds__(1024)
void k_route(const int* __restrict__ idx, int* __restrict__ counts,
             int* __restrict__ offsets, int* __restrict__ slot_tok,
             int* __restrict__ pair_slot) {
    __shared__ int cnt[NE], offs[NE], cur[NE];
    const int tid = threadIdx.x;
    if (tid < NE) cnt[tid] = 0;
    __syncthreads();
    for (int i = tid; i < T2; i += 1024) atomicAdd(&cnt[idx[i]], 1);
    __syncthreads();
    if (tid == 0) {
        int s = 0;
        for (int e = 0; e < NE; e++) {
            offs[e] = s; offsets[e] = s; counts[e] = cnt[e]; s += cnt[e];
        }
    }
    if (tid < NE) cur[tid] = 0;
    __syncthreads();
    for (int i = tid; i < T2; i += 1024) {
        int e = idx[i];
        int pos = offs[e] + atomicAdd(&cur[e], 1);
        slot_tok[pos] = i >> 1;
        pair_slot[i] = pos;
    }
}

// gather routed token rows into dense bf16 slot-major matrix Xg[slot][DM]
__global__ void k_gather(const float* __restrict__ x, const int* __restrict__ slot_tok,
                         unsigned short* __restrict__ Xg) {
    int s = blockIdx.x;
    int tok = slot_tok[s];
    const float4* src = (const float4*)(x + (size_t)tok * DM);
    ushort4* dst = (ushort4*)(Xg + (size_t)s * DM);
    for (int i = threadIdx.x; i < DM / 4; i += blockDim.x) {
        float4 v = src[i];
        ushort4 o;
        o.x = f2bf(v.x); o.y = f2bf(v.y); o.z = f2bf(v.z); o.w = f2bf(v.w);
        dst[i] = o;
    }
}

// out[t] = p1*(Y[s1]+b2[e1]) + p2*(Y[s2]+b2[e2])
__global__ void k_combine(const float* __restrict__ Y, const int* __restrict__ pair_slot,
                          const float* __restrict__ prob, const int* __restrict__ idx,
                          const float* __restrict__ b2, float* __restrict__ out) {
    int t = blockIdx.x;
    int s1 = pair_slot[t * 2], s2 = pair_slot[t * 2 + 1];
    int e1 = idx[t * 2], e2 = idx[t * 2 + 1];
    float p1 = prob[t * 2], p2 = prob[t * 2 + 1];
    const float4* y1 = (const float4*)(Y + (size_t)s1 * DM);
    const float4* y2 = (const float4*)(Y + (size_t)s2 * DM);
    const float4* ba = (const float4*)(b2 + (size_t)e1 * DM);
    const float4* bb = (const float4*)(b2 + (size_t)e2 * DM);
    float4* o = (float4*)(out + (size_t)t * DM);
    int i = threadIdx.x;
    float4 a = y1[i], b = y2[i], c = ba[i], d = bb[i];
    float4 r;
    r.x = p1 * (a.x + c.x) + p2 * (b.x + d.x);
    r.y = p1 * (a.y + c.y) + p2 * (b.y + d.y);
    r.z = p1 * (a.z + c.z) + p2 * (b.z + d.z);
    r.w = p1 * (a.w + c.w) + p2 * (b.w + d.w);
    o[i] = r;
}

// ---------------- transpose+convert: W[K][N] fp32 -> WT[N][K] bf16 ----------------
// grid (N/64, K/64, NE); 16B/lane stores, 128B per 4-lane group.

__global__ __launch_bounds__(256)
void k_convT(const float* __restrict__ W, unsigned short* __restrict__ WT,
             int K, int N) {
    const int e = blockIdx.z;
    const int n0 = blockIdx.x * 64, k0 = blockIdx.y * 64;
    W += (size_t)e * K * N;
    WT += (size_t)e * K * N;
    __shared__ float T[64][65];
    const int t = threadIdx.x;
    const int rr = t >> 4, cc = (t & 15) * 4;
#pragma unroll
    for (int p = 0; p < 4; p++) {
        float4 v = *(const float4*)(W + (size_t)(k0 + rr + p * 16) * N + n0 + cc);
        T[rr + p * 16][cc + 0] = v.x;
        T[rr + p * 16][cc + 1] = v.y;
        T[rr + p * 16][cc + 2] = v.z;
        T[rr + p * 16][cc + 3] = v.w;
    }
    __syncthreads();
    const int n = t >> 2, kb = (t & 3) * 16;
#pragma unroll
    for (int p = 0; p < 2; p++) {
        s16x8 o;
#pragma unroll
        for (int j = 0; j < 8; j++)
            o[j] = (short)f2bf(T[kb + p * 8 + j][n]);
        *(s16x8*)(WT + (size_t)(n0 + n) * K + k0 + kb + p * 8) = o;
    }
}

// ---------------- MM kernels: m97-clean loop, flat 16-fragment loads -------------
// Single 32 KB LDS buffer, plain __syncthreads, no asm fences: let hipcc emit its
// own lgkmcnt ladder. All 16 ds_read_b128 issued before the 32 MFMAs (64 operand
// VGPRs in flight -> deep schedule; R11's per-ks reuse pinned VGPR=88 = shallow).
// Involution swizzle (verified R8, conflicts==0): stage chunk (lane&7)^(lane>>3),
// read offset ((ks*4|lane>>4)^(lane&7))*16 hoisted as swz0/swz1.

__global__ __launch_bounds__(256)
void k_mm1(const unsigned short* __restrict__ Xg, const unsigned short* __restrict__ W1T,
           const float* __restrict__ b1, const int* __restrict__ counts,
           const int* __restrict__ offsets, unsigned short* __restrict__ H) {
    const int TOT = NE * MTILES * (DF / BN);                 // 6144
    int work = (blockIdx.x & 7) * (TOT >> 3) + (blockIdx.x >> 3);
    const int mt = work % MTILES;
    const int en = work / MTILES;
    const int e  = en >> 5;
    const int n0 = (en & 31) * BN;
    const int ne = counts[e];
    const int m0 = mt * BM;
    if (m0 >= ne) return;
    const int rows = min(BM, ne - m0);
    const int slotbase = offsets[e] + m0;

    __shared__ unsigned short As[BM * BK];   // 16 KB
    __shared__ unsigned short Bs[BN * BK];   // 16 KB

    const int tid  = threadIdx.x;
    const int lane = tid & 63;
    const int w    = tid >> 6;
    const int wm   = w >> 1, wn = w & 1;

    const unsigned short* bte = W1T + (size_t)e * (size_t)DF * DM;
    const int arow = lane >> 3;
    const int gchunk = ((lane & 7) ^ arow) * 8;

    const int swz0 = ((lane >> 4) ^ (lane & 7)) << 4;
    const int swz1 = ((4 | (lane >> 4)) ^ (lane & 7)) << 4;
    const char* Arow = (const char*)As + (wm * 64 + (lane & 15)) * 128;
    const char* Brow = (const char*)Bs + (wn * 64 + (lane & 15)) * 128;

    f32x4 acc[4][4];
#pragma unroll
    for (int a = 0; a < 4; a++)
#pragma unroll
        for (int b = 0; b < 4; b++) acc[a][b] = (f32x4)0.f;

#pragma unroll 1
    for (int kt = 0; kt < NK1; ++kt) {
        const int k0 = kt * BK;
#pragma unroll
        for (int q = 0; q < 4; q++) {
            int row = (w * 4 + q) * 8 + arow;
            GLL(Xg + (size_t)(slotbase + row) * DM + k0 + gchunk,
                &As[(w * 4 + q) * 512]);
            GLL(bte + (size_t)(n0 + row) * DM + k0 + gchunk,
                &Bs[(w * 4 + q) * 512]);
        }
        __syncthreads();
        s16x8 af[2][4], bfr[2][4];
#pragma unroll
        for (int f = 0; f < 4; f++) {
            af[0][f]  = *(const s16x8*)(Arow + f * 2048 + swz0);
            af[1][f]  = *(const s16x8*)(Arow + f * 2048 + swz1);
            bfr[0][f] = *(const s16x8*)(Brow + f * 2048 + swz0);
            bfr[1][f] = *(const s16x8*)(Brow + f * 2048 + swz1);
        }
#pragma unroll
        for (int ks = 0; ks < 2; ks++)
#pragma unroll
            for (int fm = 0; fm < 4; fm++)
#pragma unroll
                for (int fn = 0; fn < 4; fn++)
                    acc[fm][fn] = __builtin_amdgcn_mfma_f32_16x16x32_bf16(
                        af[ks][fm], bfr[ks][fn], acc[fm][fn], 0, 0, 0);
        __syncthreads();
    }

    const float* b1e = b1 + (size_t)e * DF;
#pragma unroll
    for (int fm = 0; fm < 4; fm++) {
        const int mrow = wm * 64 + fm * 16 + ((lane >> 4) << 2);
#pragma unroll
        for (int fn = 0; fn < 4; fn++) {
            const int ncol = n0 + wn * 64 + fn * 16 + (lane & 15);
            const float bb = b1e[ncol];
#pragma unroll
            for (int r = 0; r < 4; r++) {
                const int m = mrow + r;
                if (m < rows) {
                    float h = acc[fm][fn][r] + bb;
                    h = 0.5f * h * (1.f + erff(h * 0.70710678118654752f));
                    H[(size_t)(slotbase + m) * DF + ncol] = f2bf(h);
                }
            }
        }
    }
}

__global__ __launch_bounds__(256)
void k_mm2(const unsigned short* __restrict__ Hb, const unsigned short* __restrict__ W2T,
           const int* __restrict__ counts, const int* __restrict__ offsets,
           float* __restrict__ Y) {
    const int TOT = NE * MTILES * (DM / BN);                 // 1536
    int work = (blockIdx.x & 7) * (TOT >> 3) + (blockIdx.x >> 3);
    const int mt = work % MTILES;
    const int en = work / MTILES;
    const int e  = en >> 3;
    const int n0 = (en & 7) * BN;
    const int ne = counts[e];
    const int m0 = mt * BM;
    if (m0 >= ne) return;
    const int rows = min(BM, ne - m0);
    const int slotbase = offsets[e] + m0;

    __shared__ unsigned short As[BM * BK];
    __shared__ unsigned short Bs[BN * BK];

    const int tid  = threadIdx.x;
    const int lane = tid & 63;
    const int w    = tid >> 6;
    const int wm   = w >> 1, wn = w & 1;

    const unsigned short* bte = W2T + (size_t)e * (size_t)DF * DM;
    const int arow = lane >> 3;
    const int gchunk = ((lane & 7) ^ arow) * 8;

    const int swz0 = ((lane >> 4) ^ (lane & 7)) << 4;
    const int swz1 = ((4 | (lane >> 4)) ^ (lane & 7)) << 4;
    const char* Arow = (const char*)As + (wm * 64 + (lane & 15)) * 128;
    const char* Brow = (const char*)Bs + (wn * 64 + (lane & 15)) * 128;

    f32x4 acc[4][4];
#pragma unroll
    for (int a = 0; a < 4; a++)
#pragma unroll
        for (int b = 0; b < 4; b++) acc[a][b] = (f32x4)0.f;

#pragma unroll 1
    for (int kt = 0; kt < NK2; ++kt) {
        const int k0 = kt * BK;
#pragma unroll
        for (int q = 0; q < 4; q++) {
            int row = (w * 4 + q) * 8 + arow;
            GLL(Hb + (size_t)(slotbase + row) * DF + k0 + gchunk,
                &As[(w * 4 + q) * 512]);
            GLL(bte + (size_t)(n0 + row) * DF + k0 + gchunk,
                &Bs[(w * 4 + q) * 512]);
        }
        __syncthreads();
        s16x8 af[2][4], bfr[2][4];
#pragma unroll
        for (int f = 0; f < 4; f++) {
            af[0][f]  = *(const s16x8*)(Arow + f * 2048 + swz0);
            af[1][f]  = *(const s16x8*)(Arow + f * 2048 + swz1);
            bfr[0][f] = *(const s16x8*)(Brow + f * 2048 + swz0);
            bfr[1][f] = *(const s16x8*)(Brow + f * 2048 + swz1);
        }
#pragma unroll
        for (int ks = 0; ks < 2; ks++)
#pragma unroll
            for (int fm = 0; fm < 4; fm++)
#pragma unroll
                for (int fn = 0; fn < 4; fn++)
                    acc[fm][fn] = __builtin_amdgcn_mfma_f32_16x16x32_bf16(
                        af[ks][fm], bfr[ks][fn], acc[fm][fn], 0, 0, 0);
        __syncthreads();
    }

#pragma unroll
    for (int fm = 0; fm < 4; fm++) {
        const int mrow = wm * 64 + fm * 16 + ((lane >> 4) << 2);
#pragma unroll
        for (int fn = 0; fn < 4; fn++) {
            const int ncol = n0 + wn * 64 + fn * 16 + (lane & 15);
#pragma unroll
            for (int r = 0; r < 4; r++) {
                const int m = mrow + r;
                if (m < rows)
                    Y[(size_t)(slotbase + m) * DM + ncol] = acc[fm][fn][r];
            }
        }
    }
}

// ---------------- launch ----------------

extern "C" void kernel_launch(void* const* d_in, const int* in_sizes, int n_in,
                              void* d_out, int out_size, void* d_ws, size_t ws_size,
                              hipStream_t stream) {
    const float* x   = (const float*)d_in[0];
    const float* gw  = (const float*)d_in[1];
    const float* gb  = (const float*)d_in[2];
    const float* w1  = (const float*)d_in[3];
    const float* b1  = (const float*)d_in[4];
    const float* w2  = (const float*)d_in[5];
    const float* b2  = (const float*)d_in[6];
    float* out = (float*)d_out;

    size_t off = 0;
    auto alloc = [&](size_t bytes) {
        void* p = (char*)d_ws + off;
        off += (bytes + 255) & ~(size_t)255;
        return p;
    };
    float* gwT       = (float*)alloc(NE * DM * sizeof(float));
    int*   idx       = (int*)alloc(T2 * sizeof(int));
    float* prob      = (float*)alloc(T2 * sizeof(float));
    int*   counts    = (int*)alloc(32 * sizeof(int));
    int*   offsets   = (int*)alloc(32 * sizeof(int));
    int*   slot_tok  = (int*)alloc(T2 * sizeof(int));
    int*   pair_slot = (int*)alloc(T2 * sizeof(int));
    unsigned short* Xg = (unsigned short*)alloc((size_t)(T2 + BM) * DM * sizeof(unsigned short));
    unsigned short* Hb = (unsigned short*)alloc((size_t)(T2 + BM) * DF * sizeof(unsigned short));
    float* Yb        = (float*)alloc((size_t)(T2 + BM) * DM * sizeof(float));
    unsigned short* W1T = (unsigned short*)alloc((size_t)NE * DM * DF * sizeof(unsigned short));
    unsigned short* W2T = (unsigned short*)alloc((size_t)NE * DF * DM * sizeof(unsigned short));
    // ~523 MB total; ws_size ~1.61 GB (R5 fillBuffer evidence)

    k_transpose_gw<<<NE, 256, 0, stream>>>(gw, gwT);
    k_gate<<<T_TOK / 4, 256, 0, stream>>>(x, gwT, gb, idx, prob);
    k_route<<<1, 1024, 0, stream>>>(idx, counts, offsets, slot_tok, pair_slot);
    k_gather<<<T2, 256, 0, stream>>>(x, slot_tok, Xg);

    // convT(W1) -> mm1 -> convT(W2) -> mm2: each WT is L3-hot when consumed
    dim3 gc1(DF / 64, DM / 64, NE);
    k_convT<<<gc1, 256, 0, stream>>>(w1, W1T, DM, DF);
    k_mm1<<<NE * MTILES * (DF / BN), 256, 0, stream>>>(Xg, W1T, b1, counts, offsets, Hb);

    dim3 gc2(DM / 64, DF / 64, NE);
    k_convT<<<gc2, 256, 0, stream>>>(w2, W2T, DF, DM);
    k_mm2<<<NE * MTILES * (DM / BN), 256, 0, stream>>>(Hb, W2T, counts, offsets, Yb);

    k_combine<<<T_TOK, 256, 0, stream>>>(Yb, pair_slot, prob, idx, b2, out);
}

// Round 13
// 653.701 us; speedup vs baseline: 1.1518x; 1.0288x over previous
//
#include <hip/hip_runtime.h>
#include <math.h>

#define DM 1024
#define DF 4096
#define NE 24
#define T_TOK 4096
#define T2 (T_TOK*2)

#define BM 128
#define BN 64
#define BK 64
#define MTILES 8
#define NK1 (DM / BK)   // 16
#define NK2 (DF / BK)   // 64

typedef __attribute__((ext_vector_type(4))) float f32x4;
typedef __attribute__((ext_vector_type(8))) short s16x8;

// exact RNE fp32 -> bf16 (finite inputs)
static __device__ __forceinline__ unsigned short f2bf(float f) {
    unsigned int u = __float_as_uint(f);
    unsigned int r = u + 0x7fffu + ((u >> 16) & 1u);
    return (unsigned short)(r >> 16);
}

// async global->LDS, 16B per lane; lds dest is wave-uniform base + lane*16
#define GLL(gsrc, ldst)                                                          \
    __builtin_amdgcn_global_load_lds(                                            \
        (const __attribute__((address_space(1))) void*)(gsrc),                   \
        (__attribute__((address_space(3))) void*)(ldst), 16, 0, 0)

// ---------------- gating ----------------

__global__ void k_transpose_gw(const float* __restrict__ gw, float* __restrict__ gwT) {
    int e = blockIdx.x;
    for (int d = threadIdx.x; d < DM; d += blockDim.x)
        gwT[e * DM + d] = gw[d * NE + e];
}

__global__ void k_gate(const float* __restrict__ x, const float* __restrict__ gwT,
                       const float* __restrict__ gb,
                       int* __restrict__ idx, float* __restrict__ prob) {
    int wave = threadIdx.x >> 6;
    int lane = threadIdx.x & 63;
    int t = blockIdx.x * 4 + wave;
    if (t >= T_TOK) return;
    const float* xr = x + (size_t)t * DM;
    float acc[NE];
#pragma unroll
    for (int e = 0; e < NE; e++) acc[e] = 0.f;
    for (int i = 0; i < DM / 64; i++) {
        int d = lane + i * 64;
        float xv = xr[d];
#pragma unroll
        for (int e = 0; e < NE; e++) acc[e] = fmaf(xv, gwT[e * DM + d], acc[e]);
    }
#pragma unroll
    for (int e = 0; e < NE; e++) {
        float v = acc[e];
        for (int off = 32; off >= 1; off >>= 1) v += __shfl_xor(v, off);
        acc[e] = v;
    }
    if (lane == 0) {
        float v1 = -1e30f, v2 = -1e30f;
        int i1 = -1, i2 = -1;
        for (int e = 0; e < NE; e++) {
            float s = acc[e] + gb[e];
            if (s > v1) { v2 = v1; i2 = i1; v1 = s; i1 = e; }
            else if (s > v2) { v2 = s; i2 = e; }
        }
        float e2 = expf(v2 - v1);
        float inv = 1.f / (1.f + e2);
        idx[t * 2] = i1; idx[t * 2 + 1] = i2;
        prob[t * 2] = inv; prob[t * 2 + 1] = e2 * inv;
    }
}

// ---------------- routing: count + scan + scatter in one block ----------------

__global__ __launch_bounds__(1024)
void k_route(const int* __restrict__ idx, int* __restrict__ counts,
             int* __restrict__ offsets, int* __restrict__ slot_tok,
             int* __restrict__ pair_slot) {
    __shared__ int cnt[NE], offs[NE], cur[NE];
    const int tid = threadIdx.x;
    if (tid < NE) cnt[tid] = 0;
    __syncthreads();
    for (int i = tid; i < T2; i += 1024) atomicAdd(&cnt[idx[i]], 1);
    __syncthreads();
    if (tid == 0) {
        int s = 0;
        for (int e = 0; e < NE; e++) {
            offs[e] = s; offsets[e] = s; counts[e] = cnt[e]; s += cnt[e];
        }
    }
    if (tid < NE) cur[tid] = 0;
    __syncthreads();
    for (int i = tid; i < T2; i += 1024) {
        int e = idx[i];
        int pos = offs[e] + atomicAdd(&cur[e], 1);
        slot_tok[pos] = i >> 1;
        pair_slot[i] = pos;
    }
}

// gather routed token rows into dense bf16 slot-major matrix Xg[slot][DM]
__global__ void k_gather(const float* __restrict__ x, const int* __restrict__ slot_tok,
                         unsigned short* __restrict__ Xg) {
    int s = blockIdx.x;
    int tok = slot_tok[s];
    const float4* src = (const float4*)(x + (size_t)tok * DM);
    ushort4* dst = (ushort4*)(Xg + (size_t)s * DM);
    for (int i = threadIdx.x; i < DM / 4; i += blockDim.x) {
        float4 v = src[i];
        ushort4 o;
        o.x = f2bf(v.x); o.y = f2bf(v.y); o.z = f2bf(v.z); o.w = f2bf(v.w);
        dst[i] = o;
    }
}

// out[t] = p1*(Y[s1]+b2[e1]) + p2*(Y[s2]+b2[e2])
__global__ void k_combine(const float* __restrict__ Y, const int* __restrict__ pair_slot,
                          const float* __restrict__ prob, const int* __restrict__ idx,
                          const float* __restrict__ b2, float* __restrict__ out) {
    int t = blockIdx.x;
    int s1 = pair_slot[t * 2], s2 = pair_slot[t * 2 + 1];
    int e1 = idx[t * 2], e2 = idx[t * 2 + 1];
    float p1 = prob[t * 2], p2 = prob[t * 2 + 1];
    const float4* y1 = (const float4*)(Y + (size_t)s1 * DM);
    const float4* y2 = (const float4*)(Y + (size_t)s2 * DM);
    const float4* ba = (const float4*)(b2 + (size_t)e1 * DM);
    const float4* bb = (const float4*)(b2 + (size_t)e2 * DM);
    float4* o = (float4*)(out + (size_t)t * DM);
    int i = threadIdx.x;
    float4 a = y1[i], b = y2[i], c = ba[i], d = bb[i];
    float4 r;
    r.x = p1 * (a.x + c.x) + p2 * (b.x + d.x);
    r.y = p1 * (a.y + c.y) + p2 * (b.y + d.y);
    r.z = p1 * (a.z + c.z) + p2 * (b.z + d.z);
    r.w = p1 * (a.w + c.w) + p2 * (b.w + d.w);
    o[i] = r;
}

// ---------------- fused transpose+convert: W[K][N] fp32 -> WT[N][K] bf16 --------
// one dispatch for W1 (z<NE) and W2 (z>=NE); 64x64 tiles; 16B/lane stores.
// (proven correct in R7 run)

__global__ __launch_bounds__(256)
void k_conv(const float* __restrict__ w1, const float* __restrict__ w2,
            unsigned short* __restrict__ W1T, unsigned short* __restrict__ W2T) {
    const int z = blockIdx.y;
    const float* W;
    unsigned short* WT;
    int K, N, n0, k0;
    if (z < NE) {
        W = w1 + (size_t)z * DM * DF;  WT = W1T + (size_t)z * DM * DF;
        K = DM; N = DF;
        n0 = (blockIdx.x & 63) * 64;  k0 = (blockIdx.x >> 6) * 64;
    } else {
        W = w2 + (size_t)(z - NE) * DF * DM;  WT = W2T + (size_t)(z - NE) * DF * DM;
        K = DF; N = DM;
        n0 = (blockIdx.x & 15) * 64;  k0 = (blockIdx.x >> 4) * 64;
    }
    __shared__ float T[64][65];
    const int t = threadIdx.x;
    const int rr = t >> 4, cc = (t & 15) * 4;
#pragma unroll
    for (int p = 0; p < 4; p++) {
        float4 v = *(const float4*)(W + (size_t)(k0 + rr + p * 16) * N + n0 + cc);
        T[rr + p * 16][cc + 0] = v.x;
        T[rr + p * 16][cc + 1] = v.y;
        T[rr + p * 16][cc + 2] = v.z;
        T[rr + p * 16][cc + 3] = v.w;
    }
    __syncthreads();
    const int n = t >> 2, kb = (t & 3) * 16;
#pragma unroll
    for (int p = 0; p < 2; p++) {
        s16x8 o;
#pragma unroll
        for (int j = 0; j < 8; j++)
            o[j] = (short)f2bf(T[kb + p * 8 + j][n]);
        *(s16x8*)(WT + (size_t)(n0 + n) * K + k0 + kb + p * 8) = o;
    }
}

// ---------------- MM kernels: 128x64 tile, m97-clean loop, occupancy play --------
// BN=64: acc 4x2 (32 AGPR), LDS 24KB, grid 2x -> target 3-5 resident blocks/CU so
// cross-block overlap (m114) hides the stage/drain latency the schedule levers
// (R9/R11 null) could not. Involution swizzle retained (conflicts==0, R8).

__global__ __launch_bounds__(256)
void k_mm1(const unsigned short* __restrict__ Xg, const unsigned short* __restrict__ W1T,
           const float* __restrict__ b1, const int* __restrict__ counts,
           const int* __restrict__ offsets, unsigned short* __restrict__ H) {
    const int TOT = NE * MTILES * (DF / BN);                 // 12288
    int work = (blockIdx.x & 7) * (TOT >> 3) + (blockIdx.x >> 3);
    const int mt = work % MTILES;
    const int en = work / MTILES;
    const int e  = en >> 6;                                  // /(DF/BN=64)
    const int n0 = (en & 63) * BN;
    const int ne = counts[e];
    const int m0 = mt * BM;
    if (m0 >= ne) return;
    const int rows = min(BM, ne - m0);
    const int slotbase = offsets[e] + m0;

    __shared__ unsigned short As[BM * BK];   // 16 KB
    __shared__ unsigned short Bs[BN * BK];   // 8 KB

    const int tid  = threadIdx.x;
    const int lane = tid & 63;
    const int w    = tid >> 6;
    const int wm   = w >> 1, wn = w & 1;

    const unsigned short* bte = W1T + (size_t)e * (size_t)DF * DM;
    const int arow = lane >> 3;
    const int gchunk = ((lane & 7) ^ arow) * 8;

    const int swz0 = ((lane >> 4) ^ (lane & 7)) << 4;
    const int swz1 = ((4 | (lane >> 4)) ^ (lane & 7)) << 4;
    const char* Arow = (const char*)As + (wm * 64 + (lane & 15)) * 128;
    const char* Brow = (const char*)Bs + (wn * 32 + (lane & 15)) * 128;

    f32x4 acc[4][2];
#pragma unroll
    for (int a = 0; a < 4; a++)
#pragma unroll
        for (int b = 0; b < 2; b++) acc[a][b] = (f32x4)0.f;

#pragma unroll 1
    for (int kt = 0; kt < NK1; ++kt) {
        const int k0 = kt * BK;
#pragma unroll
        for (int q = 0; q < 4; q++) {
            int row = (w * 4 + q) * 8 + arow;
            GLL(Xg + (size_t)(slotbase + row) * DM + k0 + gchunk,
                &As[(w * 4 + q) * 512]);
        }
#pragma unroll
        for (int q = 0; q < 2; q++) {
            int row = (w * 2 + q) * 8 + arow;
            GLL(bte + (size_t)(n0 + row) * DM + k0 + gchunk,
                &Bs[(w * 2 + q) * 512]);
        }
        __syncthreads();
        s16x8 af[2][4], bfr[2][2];
#pragma unroll
        for (int f = 0; f < 4; f++) {
            af[0][f] = *(const s16x8*)(Arow + f * 2048 + swz0);
            af[1][f] = *(const s16x8*)(Arow + f * 2048 + swz1);
        }
#pragma unroll
        for (int f = 0; f < 2; f++) {
            bfr[0][f] = *(const s16x8*)(Brow + f * 2048 + swz0);
            bfr[1][f] = *(const s16x8*)(Brow + f * 2048 + swz1);
        }
#pragma unroll
        for (int ks = 0; ks < 2; ks++)
#pragma unroll
            for (int fm = 0; fm < 4; fm++)
#pragma unroll
                for (int fn = 0; fn < 2; fn++)
                    acc[fm][fn] = __builtin_amdgcn_mfma_f32_16x16x32_bf16(
                        af[ks][fm], bfr[ks][fn], acc[fm][fn], 0, 0, 0);
        __syncthreads();
    }

    const float* b1e = b1 + (size_t)e * DF;
#pragma unroll
    for (int fm = 0; fm < 4; fm++) {
        const int mrow = wm * 64 + fm * 16 + ((lane >> 4) << 2);
#pragma unroll
        for (int fn = 0; fn < 2; fn++) {
            const int ncol = n0 + wn * 32 + fn * 16 + (lane & 15);
            const float bb = b1e[ncol];
#pragma unroll
            for (int r = 0; r < 4; r++) {
                const int m = mrow + r;
                if (m < rows) {
                    float h = acc[fm][fn][r] + bb;
                    h = 0.5f * h * (1.f + erff(h * 0.70710678118654752f));
                    H[(size_t)(slotbase + m) * DF + ncol] = f2bf(h);
                }
            }
        }
    }
}

__global__ __launch_bounds__(256)
void k_mm2(const unsigned short* __restrict__ Hb, const unsigned short* __restrict__ W2T,
           const int* __restrict__ counts, const int* __restrict__ offsets,
           float* __restrict__ Y) {
    const int TOT = NE * MTILES * (DM / BN);                 // 3072
    int work = (blockIdx.x & 7) * (TOT >> 3) + (blockIdx.x >> 3);
    const int mt = work % MTILES;
    const int en = work / MTILES;
    const int e  = en >> 4;                                  // /(DM/BN=16)
    const int n0 = (en & 15) * BN;
    const int ne = counts[e];
    const int m0 = mt * BM;
    if (m0 >= ne) return;
    const int rows = min(BM, ne - m0);
    const int slotbase = offsets[e] + m0;

    __shared__ unsigned short As[BM * BK];
    __shared__ unsigned short Bs[BN * BK];

    const int tid  = threadIdx.x;
    const int lane = tid & 63;
    const int w    = tid >> 6;
    const int wm   = w >> 1, wn = w & 1;

    const unsigned short* bte = W2T + (size_t)e * (size_t)DF * DM;
    const int arow = lane >> 3;
    const int gchunk = ((lane & 7) ^ arow) * 8;

    const int swz0 = ((lane >> 4) ^ (lane & 7)) << 4;
    const int swz1 = ((4 | (lane >> 4)) ^ (lane & 7)) << 4;
    const char* Arow = (const char*)As + (wm * 64 + (lane & 15)) * 128;
    const char* Brow = (const char*)Bs + (wn * 32 + (lane & 15)) * 128;

    f32x4 acc[4][2];
#pragma unroll
    for (int a = 0; a < 4; a++)
#pragma unroll
        for (int b = 0; b < 2; b++) acc[a][b] = (f32x4)0.f;

#pragma unroll 1
    for (int kt = 0; kt < NK2; ++kt) {
        const int k0 = kt * BK;
#pragma unroll
        for (int q = 0; q < 4; q++) {
            int row = (w * 4 + q) * 8 + arow;
            GLL(Hb + (size_t)(slotbase + row) * DF + k0 + gchunk,
                &As[(w * 4 + q) * 512]);
        }
#pragma unroll
        for (int q = 0; q < 2; q++) {
            int row = (w * 2 + q) * 8 + arow;
            GLL(bte + (size_t)(n0 + row) * DF + k0 + gchunk,
                &Bs[(w * 2 + q) * 512]);
        }
        __syncthreads();
        s16x8 af[2][4], bfr[2][2];
#pragma unroll
        for (int f = 0; f < 4; f++) {
            af[0][f] = *(const s16x8*)(Arow + f * 2048 + swz0);
            af[1][f] = *(const s16x8*)(Arow + f * 2048 + swz1);
        }
#pragma unroll
        for (int f = 0; f < 2; f++) {
            bfr[0][f] = *(const s16x8*)(Brow + f * 2048 + swz0);
            bfr[1][f] = *(const s16x8*)(Brow + f * 2048 + swz1);
        }
#pragma unroll
        for (int ks = 0; ks < 2; ks++)
#pragma unroll
            for (int fm = 0; fm < 4; fm++)
#pragma unroll
                for (int fn = 0; fn < 2; fn++)
                    acc[fm][fn] = __builtin_amdgcn_mfma_f32_16x16x32_bf16(
                        af[ks][fm], bfr[ks][fn], acc[fm][fn], 0, 0, 0);
        __syncthreads();
    }

#pragma unroll
    for (int fm = 0; fm < 4; fm++) {
        const int mrow = wm * 64 + fm * 16 + ((lane >> 4) << 2);
#pragma unroll
        for (int fn = 0; fn < 2; fn++) {
            const int ncol = n0 + wn * 32 + fn * 16 + (lane & 15);
#pragma unroll
            for (int r = 0; r < 4; r++) {
                const int m = mrow + r;
                if (m < rows)
                    Y[(size_t)(slotbase + m) * DM + ncol] = acc[fm][fn][r];
            }
        }
    }
}

// ---------------- launch ----------------

extern "C" void kernel_launch(void* const* d_in, const int* in_sizes, int n_in,
                              void* d_out, int out_size, void* d_ws, size_t ws_size,
                              hipStream_t stream) {
    const float* x   = (const float*)d_in[0];
    const float* gw  = (const float*)d_in[1];
    const float* gb  = (const float*)d_in[2];
    const float* w1  = (const float*)d_in[3];
    const float* b1  = (const float*)d_in[4];
    const float* w2  = (const float*)d_in[5];
    const float* b2  = (const float*)d_in[6];
    float* out = (float*)d_out;

    size_t off = 0;
    auto alloc = [&](size_t bytes) {
        void* p = (char*)d_ws + off;
        off += (bytes + 255) & ~(size_t)255;
        return p;
    };
    float* gwT       = (float*)alloc(NE * DM * sizeof(float));
    int*   idx       = (int*)alloc(T2 * sizeof(int));
    float* prob      = (float*)alloc(T2 * sizeof(float));
    int*   counts    = (int*)alloc(32 * sizeof(int));
    int*   offsets   = (int*)alloc(32 * sizeof(int));
    int*   slot_tok  = (int*)alloc(T2 * sizeof(int));
    int*   pair_slot = (int*)alloc(T2 * sizeof(int));
    unsigned short* Xg = (unsigned short*)alloc((size_t)(T2 + BM) * DM * sizeof(unsigned short));
    unsigned short* Hb = (unsigned short*)alloc((size_t)(T2 + BM) * DF * sizeof(unsigned short));
    float* Yb        = (float*)alloc((size_t)(T2 + BM) * DM * sizeof(float));
    unsigned short* W1T = (unsigned short*)alloc((size_t)NE * DM * DF * sizeof(unsigned short));
    unsigned short* W2T = (unsigned short*)alloc((size_t)NE * DF * DM * sizeof(unsigned short));
    // ~523 MB total; ws_size ~1.61 GB (R5 fillBuffer evidence)

    k_transpose_gw<<<NE, 256, 0, stream>>>(gw, gwT);
    k_gate<<<T_TOK / 4, 256, 0, stream>>>(x, gwT, gb, idx, prob);
    k_route<<<1, 1024, 0, stream>>>(idx, counts, offsets, slot_tok, pair_slot);
    k_gather<<<T2, 256, 0, stream>>>(x, slot_tok, Xg);

    dim3 gc(1024, NE * 2);
    k_conv<<<gc, 256, 0, stream>>>(w1, w2, W1T, W2T);

    k_mm1<<<NE * MTILES * (DF / BN), 256, 0, stream>>>(Xg, W1T, b1, counts, offsets, Hb);
    k_mm2<<<NE * MTILES * (DM / BN), 256, 0, stream>>>(Hb, W2T, counts, offsets, Yb);
    k_combine<<<T_TOK, 256, 0, stream>>>(Yb, pair_slot, prob, idx, b2, out);
}

// Round 14
// 574.654 us; speedup vs baseline: 1.3102x; 1.1376x over previous
//
#include <hip/hip_runtime.h>
#include <math.h>

#define DM 1024
#define DF 4096
#define NE 24
#define T_TOK 4096
#define T2 (T_TOK*2)

#define BM 128
#define BN 64
#define BK 64
#define MTILES 8
#define NK1 (DM / BK)   // 16
#define NK2 (DF / BK)   // 64

typedef __attribute__((ext_vector_type(4))) float f32x4;
typedef __attribute__((ext_vector_type(8))) short s16x8;

// exact RNE fp32 -> bf16 (finite inputs)
static __device__ __forceinline__ unsigned short f2bf(float f) {
    unsigned int u = __float_as_uint(f);
    unsigned int r = u + 0x7fffu + ((u >> 16) & 1u);
    return (unsigned short)(r >> 16);
}

// async global->LDS, 16B per lane; lds dest is wave-uniform base + lane*16
#define GLL(gsrc, ldst)                                                          \
    __builtin_amdgcn_global_load_lds(                                            \
        (const __attribute__((address_space(1))) void*)(gsrc),                   \
        (__attribute__((address_space(3))) void*)(ldst), 16, 0, 0)

// ---------------- gating ----------------

__global__ void k_transpose_gw(const float* __restrict__ gw, float* __restrict__ gwT) {
    int e = blockIdx.x;
    for (int d = threadIdx.x; d < DM; d += blockDim.x)
        gwT[e * DM + d] = gw[d * NE + e];
}

__global__ void k_gate(const float* __restrict__ x, const float* __restrict__ gwT,
                       const float* __restrict__ gb,
                       int* __restrict__ idx, float* __restrict__ prob) {
    int wave = threadIdx.x >> 6;
    int lane = threadIdx.x & 63;
    int t = blockIdx.x * 4 + wave;
    if (t >= T_TOK) return;
    const float* xr = x + (size_t)t * DM;
    float acc[NE];
#pragma unroll
    for (int e = 0; e < NE; e++) acc[e] = 0.f;
    for (int i = 0; i < DM / 64; i++) {
        int d = lane + i * 64;
        float xv = xr[d];
#pragma unroll
        for (int e = 0; e < NE; e++) acc[e] = fmaf(xv, gwT[e * DM + d], acc[e]);
    }
#pragma unroll
    for (int e = 0; e < NE; e++) {
        float v = acc[e];
        for (int off = 32; off >= 1; off >>= 1) v += __shfl_xor(v, off);
        acc[e] = v;
    }
    if (lane == 0) {
        float v1 = -1e30f, v2 = -1e30f;
        int i1 = -1, i2 = -1;
        for (int e = 0; e < NE; e++) {
            float s = acc[e] + gb[e];
            if (s > v1) { v2 = v1; i2 = i1; v1 = s; i1 = e; }
            else if (s > v2) { v2 = s; i2 = e; }
        }
        float e2 = expf(v2 - v1);
        float inv = 1.f / (1.f + e2);
        idx[t * 2] = i1; idx[t * 2 + 1] = i2;
        prob[t * 2] = inv; prob[t * 2 + 1] = e2 * inv;
    }
}

// ---------------- routing: count + scan + scatter in one block ----------------

__global__ __launch_bounds__(1024)
void k_route(const int* __restrict__ idx, int* __restrict__ counts,
             int* __restrict__ offsets, int* __restrict__ slot_tok,
             int* __restrict__ pair_slot) {
    __shared__ int cnt[NE], offs[NE], cur[NE];
    const int tid = threadIdx.x;
    if (tid < NE) cnt[tid] = 0;
    __syncthreads();
    for (int i = tid; i < T2; i += 1024) atomicAdd(&cnt[idx[i]], 1);
    __syncthreads();
    if (tid == 0) {
        int s = 0;
        for (int e = 0; e < NE; e++) {
            offs[e] = s; offsets[e] = s; counts[e] = cnt[e]; s += cnt[e];
        }
    }
    if (tid < NE) cur[tid] = 0;
    __syncthreads();
    for (int i = tid; i < T2; i += 1024) {
        int e = idx[i];
        int pos = offs[e] + atomicAdd(&cur[e], 1);
        slot_tok[pos] = i >> 1;
        pair_slot[i] = pos;
    }
}

// gather routed token rows into dense bf16 slot-major matrix Xg[slot][DM]
__global__ void k_gather(const float* __restrict__ x, const int* __restrict__ slot_tok,
                         unsigned short* __restrict__ Xg) {
    int s = blockIdx.x;
    int tok = slot_tok[s];
    const float4* src = (const float4*)(x + (size_t)tok * DM);
    ushort4* dst = (ushort4*)(Xg + (size_t)s * DM);
    for (int i = threadIdx.x; i < DM / 4; i += blockDim.x) {
        float4 v = src[i];
        ushort4 o;
        o.x = f2bf(v.x); o.y = f2bf(v.y); o.z = f2bf(v.z); o.w = f2bf(v.w);
        dst[i] = o;
    }
}

// out[t] = p1*(Y[s1]+b2[e1]) + p2*(Y[s2]+b2[e2])
__global__ void k_combine(const float* __restrict__ Y, const int* __restrict__ pair_slot,
                          const float* __restrict__ prob, const int* __restrict__ idx,
                          const float* __restrict__ b2, float* __restrict__ out) {
    int t = blockIdx.x;
    int s1 = pair_slot[t * 2], s2 = pair_slot[t * 2 + 1];
    int e1 = idx[t * 2], e2 = idx[t * 2 + 1];
    float p1 = prob[t * 2], p2 = prob[t * 2 + 1];
    const float4* y1 = (const float4*)(Y + (size_t)s1 * DM);
    const float4* y2 = (const float4*)(Y + (size_t)s2 * DM);
    const float4* ba = (const float4*)(b2 + (size_t)e1 * DM);
    const float4* bb = (const float4*)(b2 + (size_t)e2 * DM);
    float4* o = (float4*)(out + (size_t)t * DM);
    int i = threadIdx.x;
    float4 a = y1[i], b = y2[i], c = ba[i], d = bb[i];
    float4 r;
    r.x = p1 * (a.x + c.x) + p2 * (b.x + d.x);
    r.y = p1 * (a.y + c.y) + p2 * (b.y + d.y);
    r.z = p1 * (a.z + c.z) + p2 * (b.z + d.z);
    r.w = p1 * (a.w + c.w) + p2 * (b.w + d.w);
    o[i] = r;
}

// ---------------- MM kernels: fused fp32->bf16 B-conversion in-kernel ------------
// Per K-step: GLL A (bf16) + GLL B (fp32 [k][n] tile, zero regs) -> sync ->
// {A-frag reads || B convert: 16 scalar column b32 reads (2-way, free) + f2bf +
// 2 swizzled b128 writes} -> sync -> B-frag reads + 16 MFMA -> sync.
// Involution swizzle on As/Bs retained (R8: conflicts==0). No W pre-pass.

__global__ __launch_bounds__(256)
void k_mm1(const unsigned short* __restrict__ Xg, const float* __restrict__ w1,
           const float* __restrict__ b1, const int* __restrict__ counts,
           const int* __restrict__ offsets, unsigned short* __restrict__ H) {
    const int TOT = NE * MTILES * (DF / BN);                 // 12288
    int work = (blockIdx.x & 7) * (TOT >> 3) + (blockIdx.x >> 3);
    const int mt = work % MTILES;
    const int en = work / MTILES;
    const int e  = en >> 6;                                  // /(DF/BN=64)
    const int n0 = (en & 63) * BN;
    const int ne = counts[e];
    const int m0 = mt * BM;
    if (m0 >= ne) return;
    const int rows = min(BM, ne - m0);
    const int slotbase = offsets[e] + m0;

    __shared__ unsigned short As[BM * BK];   // 16 KB bf16 [m][k] swizzled
    __shared__ float          Bf[BN * BK];   // 16 KB fp32 [k][n] linear
    __shared__ unsigned short Bs[BN * BK];   // 8 KB  bf16 [n][k] swizzled

    const int tid  = threadIdx.x;
    const int lane = tid & 63;
    const int w    = tid >> 6;
    const int wm   = w >> 1, wn = w & 1;

    const float* w1e = w1 + (size_t)e * DM * DF;
    const int arow = lane >> 3;
    const int gchunk = ((lane & 7) ^ arow) * 8;

    const int swz0 = ((lane >> 4) ^ (lane & 7)) << 4;
    const int swz1 = ((4 | (lane >> 4)) ^ (lane & 7)) << 4;
    const char* Arow = (const char*)As + (wm * 64 + (lane & 15)) * 128;
    const char* Brow = (const char*)Bs + (wn * 32 + (lane & 15)) * 128;

    // conversion-phase mapping: n = lane, k-strip = wave*16
    const int cn = lane;
    const int ck = w * 16;
    const int cc0 = ((ck >> 3) ^ (cn & 7)) << 4;
    const int cc1 = (((ck >> 3) + 1) ^ (cn & 7)) << 4;
    char* BsRowC = (char*)Bs + cn * 128;

    f32x4 acc[4][2];
#pragma unroll
    for (int a = 0; a < 4; a++)
#pragma unroll
        for (int b = 0; b < 2; b++) acc[a][b] = (f32x4)0.f;

#pragma unroll 1
    for (int kt = 0; kt < NK1; ++kt) {
        const int k0 = kt * BK;
        // A: bf16, involution-preswizzled source chunks
#pragma unroll
        for (int q = 0; q < 4; q++) {
            int row = (w * 4 + q) * 8 + arow;
            GLL(Xg + (size_t)(slotbase + row) * DM + k0 + gchunk,
                &As[(w * 4 + q) * 512]);
        }
        // B: fp32 [k][n] tile, linear (wave w covers k-rows w*16..w*16+15)
#pragma unroll
        for (int q = 0; q < 4; q++) {
            GLL(w1e + (size_t)(k0 + w * 16 + q * 4 + (lane >> 4)) * DF + n0 + (lane & 15) * 4,
                &Bf[(w * 16 + q * 4) * 64]);
        }
        __syncthreads();
        // A-frag reads (As ready) overlap B conversion
        s16x8 af[2][4];
#pragma unroll
        for (int f = 0; f < 4; f++) {
            af[0][f] = *(const s16x8*)(Arow + f * 2048 + swz0);
            af[1][f] = *(const s16x8*)(Arow + f * 2048 + swz1);
        }
        {
            s16x8 v0, v1;
#pragma unroll
            for (int j = 0; j < 8; j++)
                v0[j] = (short)f2bf(Bf[(ck + j) * 64 + cn]);
#pragma unroll
            for (int j = 0; j < 8; j++)
                v1[j] = (short)f2bf(Bf[(ck + 8 + j) * 64 + cn]);
            *(s16x8*)(BsRowC + cc0) = v0;
            *(s16x8*)(BsRowC + cc1) = v1;
        }
        __syncthreads();
        s16x8 bfr[2][2];
#pragma unroll
        for (int f = 0; f < 2; f++) {
            bfr[0][f] = *(const s16x8*)(Brow + f * 2048 + swz0);
            bfr[1][f] = *(const s16x8*)(Brow + f * 2048 + swz1);
        }
#pragma unroll
        for (int ks = 0; ks < 2; ks++)
#pragma unroll
            for (int fm = 0; fm < 4; fm++)
#pragma unroll
                for (int fn = 0; fn < 2; fn++)
                    acc[fm][fn] = __builtin_amdgcn_mfma_f32_16x16x32_bf16(
                        af[ks][fm], bfr[ks][fn], acc[fm][fn], 0, 0, 0);
        __syncthreads();
    }

    const float* b1e = b1 + (size_t)e * DF;
#pragma unroll
    for (int fm = 0; fm < 4; fm++) {
        const int mrow = wm * 64 + fm * 16 + ((lane >> 4) << 2);
#pragma unroll
        for (int fn = 0; fn < 2; fn++) {
            const int ncol = n0 + wn * 32 + fn * 16 + (lane & 15);
            const float bb = b1e[ncol];
#pragma unroll
            for (int r = 0; r < 4; r++) {
                const int m = mrow + r;
                if (m < rows) {
                    float h = acc[fm][fn][r] + bb;
                    h = 0.5f * h * (1.f + erff(h * 0.70710678118654752f));
                    H[(size_t)(slotbase + m) * DF + ncol] = f2bf(h);
                }
            }
        }
    }
}

__global__ __launch_bounds__(256)
void k_mm2(const unsigned short* __restrict__ Hb, const float* __restrict__ w2,
           const int* __restrict__ counts, const int* __restrict__ offsets,
           float* __restrict__ Y) {
    const int TOT = NE * MTILES * (DM / BN);                 // 3072
    int work = (blockIdx.x & 7) * (TOT >> 3) + (blockIdx.x >> 3);
    const int mt = work % MTILES;
    const int en = work / MTILES;
    const int e  = en >> 4;                                  // /(DM/BN=16)
    const int n0 = (en & 15) * BN;
    const int ne = counts[e];
    const int m0 = mt * BM;
    if (m0 >= ne) return;
    const int rows = min(BM, ne - m0);
    const int slotbase = offsets[e] + m0;

    __shared__ unsigned short As[BM * BK];
    __shared__ float          Bf[BN * BK];
    __shared__ unsigned short Bs[BN * BK];

    const int tid  = threadIdx.x;
    const int lane = tid & 63;
    const int w    = tid >> 6;
    const int wm   = w >> 1, wn = w & 1;

    const float* w2e = w2 + (size_t)e * DF * DM;
    const int arow = lane >> 3;
    const int gchunk = ((lane & 7) ^ arow) * 8;

    const int swz0 = ((lane >> 4) ^ (lane & 7)) << 4;
    const int swz1 = ((4 | (lane >> 4)) ^ (lane & 7)) << 4;
    const char* Arow = (const char*)As + (wm * 64 + (lane & 15)) * 128;
    const char* Brow = (const char*)Bs + (wn * 32 + (lane & 15)) * 128;

    const int cn = lane;
    const int ck = w * 16;
    const int cc0 = ((ck >> 3) ^ (cn & 7)) << 4;
    const int cc1 = (((ck >> 3) + 1) ^ (cn & 7)) << 4;
    char* BsRowC = (char*)Bs + cn * 128;

    f32x4 acc[4][2];
#pragma unroll
    for (int a = 0; a < 4; a++)
#pragma unroll
        for (int b = 0; b < 2; b++) acc[a][b] = (f32x4)0.f;

#pragma unroll 1
    for (int kt = 0; kt < NK2; ++kt) {
        const int k0 = kt * BK;
#pragma unroll
        for (int q = 0; q < 4; q++) {
            int row = (w * 4 + q) * 8 + arow;
            GLL(Hb + (size_t)(slotbase + row) * DF + k0 + gchunk,
                &As[(w * 4 + q) * 512]);
        }
#pragma unroll
        for (int q = 0; q < 4; q++) {
            GLL(w2e + (size_t)(k0 + w * 16 + q * 4 + (lane >> 4)) * DM + n0 + (lane & 15) * 4,
                &Bf[(w * 16 + q * 4) * 64]);
        }
        __syncthreads();
        s16x8 af[2][4];
#pragma unroll
        for (int f = 0; f < 4; f++) {
            af[0][f] = *(const s16x8*)(Arow + f * 2048 + swz0);
            af[1][f] = *(const s16x8*)(Arow + f * 2048 + swz1);
        }
        {
            s16x8 v0, v1;
#pragma unroll
            for (int j = 0; j < 8; j++)
                v0[j] = (short)f2bf(Bf[(ck + j) * 64 + cn]);
#pragma unroll
            for (int j = 0; j < 8; j++)
                v1[j] = (short)f2bf(Bf[(ck + 8 + j) * 64 + cn]);
            *(s16x8*)(BsRowC + cc0) = v0;
            *(s16x8*)(BsRowC + cc1) = v1;
        }
        __syncthreads();
        s16x8 bfr[2][2];
#pragma unroll
        for (int f = 0; f < 2; f++) {
            bfr[0][f] = *(const s16x8*)(Brow + f * 2048 + swz0);
            bfr[1][f] = *(const s16x8*)(Brow + f * 2048 + swz1);
        }
#pragma unroll
        for (int ks = 0; ks < 2; ks++)
#pragma unroll
            for (int fm = 0; fm < 4; fm++)
#pragma unroll
                for (int fn = 0; fn < 2; fn++)
                    acc[fm][fn] = __builtin_amdgcn_mfma_f32_16x16x32_bf16(
                        af[ks][fm], bfr[ks][fn], acc[fm][fn], 0, 0, 0);
        __syncthreads();
    }

#pragma unroll
    for (int fm = 0; fm < 4; fm++) {
        const int mrow = wm * 64 + fm * 16 + ((lane >> 4) << 2);
#pragma unroll
        for (int fn = 0; fn < 2; fn++) {
            const int ncol = n0 + wn * 32 + fn * 16 + (lane & 15);
#pragma unroll
            for (int r = 0; r < 4; r++) {
                const int m = mrow + r;
                if (m < rows)
                    Y[(size_t)(slotbase + m) * DM + ncol] = acc[fm][fn][r];
            }
        }
    }
}

// ---------------- launch ----------------

extern "C" void kernel_launch(void* const* d_in, const int* in_sizes, int n_in,
                              void* d_out, int out_size, void* d_ws, size_t ws_size,
                              hipStream_t stream) {
    const float* x   = (const float*)d_in[0];
    const float* gw  = (const float*)d_in[1];
    const float* gb  = (const float*)d_in[2];
    const float* w1  = (const float*)d_in[3];
    const float* b1  = (const float*)d_in[4];
    const float* w2  = (const float*)d_in[5];
    const float* b2  = (const float*)d_in[6];
    float* out = (float*)d_out;

    size_t off = 0;
    auto alloc = [&](size_t bytes) {
        void* p = (char*)d_ws + off;
        off += (bytes + 255) & ~(size_t)255;
        return p;
    };
    float* gwT       = (float*)alloc(NE * DM * sizeof(float));
    int*   idx       = (int*)alloc(T2 * sizeof(int));
    float* prob      = (float*)alloc(T2 * sizeof(float));
    int*   counts    = (int*)alloc(32 * sizeof(int));
    int*   offsets   = (int*)alloc(32 * sizeof(int));
    int*   slot_tok  = (int*)alloc(T2 * sizeof(int));
    int*   pair_slot = (int*)alloc(T2 * sizeof(int));
    unsigned short* Xg = (unsigned short*)alloc((size_t)(T2 + BM) * DM * sizeof(unsigned short));
    unsigned short* Hb = (unsigned short*)alloc((size_t)(T2 + BM) * DF * sizeof(unsigned short));
    float* Yb        = (float*)alloc((size_t)(T2 + BM) * DM * sizeof(float));
    // ~120 MB total; no weight pre-pass buffers needed anymore

    k_transpose_gw<<<NE, 256, 0, stream>>>(gw, gwT);
    k_gate<<<T_TOK / 4, 256, 0, stream>>>(x, gwT, gb, idx, prob);
    k_route<<<1, 1024, 0, stream>>>(idx, counts, offsets, slot_tok, pair_slot);
    k_gather<<<T2, 256, 0, stream>>>(x, slot_tok, Xg);

    k_mm1<<<NE * MTILES * (DF / BN), 256, 0, stream>>>(Xg, w1, b1, counts, offsets, Hb);
    k_mm2<<<NE * MTILES * (DM / BN), 256, 0, stream>>>(Hb, w2, counts, offsets, Yb);
    k_combine<<<T_TOK, 256, 0, stream>>>(Yb, pair_slot, prob, idx, b2, out);
}